// Round 1
// 1208.594 us; speedup vs baseline: 1.1467x; 1.1467x over previous
//
#include <hip/hip_runtime.h>
#include <hip/hip_bf16.h>

// TKMDAttention on MI355X — round 8: spatial_kernel rewritten with split-bf16
// MFMA for QK^T and P·V (was scalar VALU, MfmaUtil=0, 2x220us). Softmax top-k
// (bitonic) structure unchanged. Other kernels identical to round 7.
// Shapes: b=2, C=384, H=W=128, heads=8, ch=48, crop=8, N=64.
// windowstoimg: token n of window (wy,wx) -> y = wy*8+(wx>>1), x = (wx&1)*64+n.
// top-k rule (tie-exact): keep i for k iff a_i >= k-th largest (ref "a >= kth").

#define HW 16384
#define CDIM 384
#define NHEADS 8
#define CH 48

typedef __hip_bfloat16 bf16;
typedef __attribute__((ext_vector_type(8))) short short8;
typedef __attribute__((ext_vector_type(4))) float f32x4;

static __device__ __forceinline__ unsigned short f2bf_bits(float v) {
  bf16 b = __float2bfloat16(v);
  return __builtin_bit_cast(unsigned short, b);
}
static __device__ __forceinline__ float bfbits2f(unsigned short u) {
  return __bfloat162float(__builtin_bit_cast(bf16, u));
}

// ---- weight decompose: v = hi(bf16) + lo(bf16) ----
__global__ __launch_bounds__(256) void decomp_w(const float* __restrict__ src,
                                                unsigned short* __restrict__ h,
                                                unsigned short* __restrict__ l, int n) {
  int i = blockIdx.x * 256 + threadIdx.x;
  if (i >= n) return;
  float v = src[i];
  unsigned short hb = f2bf_bits(v);
  h[i] = hb;
  l[i] = f2bf_bits(v - bfbits2f(hb));
}

// ---- transpose src[384][16384] fp32 -> fragment-order bf16 hi/lo ----
__global__ __launch_bounds__(256) void transpose_frag(const float* __restrict__ src,
                                                      short8* __restrict__ dh,
                                                      short8* __restrict__ dl) {
  const int o = blockIdx.x * 256 + threadIdx.x;  // [0, 786432)
  const int ptile = o / 768;
  const int rem = o - ptile * 768;
  const int kc = rem >> 6, lane = rem & 63;
  const int p = ptile * 16 + (lane & 15);
  const int kb = kc * 32 + (lane >> 4) * 8;
  short8 hh, ll;
#pragma unroll
  for (int j = 0; j < 8; j++) {
    float v = src[(size_t)(kb + j) * HW + p];
    unsigned short hb = f2bf_bits(v);
    hh[j] = (short)hb;
    ll[j] = (short)f2bf_bits(v - bfbits2f(hb));
  }
  dh[o] = hh;
  dl[o] = ll;
}

// ---- split-bf16 MFMA GEMM: Out[oc][p] = sum_k W[oc][k] X[k][p], K=384 ----
__global__ __launch_bounds__(256, 2) void gemm_mfma(const unsigned short* __restrict__ Wh,
                                                    const unsigned short* __restrict__ Wl,
                                                    const short8* __restrict__ Xh,
                                                    const short8* __restrict__ Xl,
                                                    float* __restrict__ Out) {
  const int tid = threadIdx.x;
  const int wave = tid >> 6, lane = tid & 63;
  const int lm = lane & 15, lq = lane >> 4;
  const int p0 = blockIdx.x * 128;
  const int oc0 = blockIdx.y * 64;
  const int pt0 = blockIdx.x * 8 + wave * 2;
  f32x4 acc[4][2] = {};
#pragma unroll
  for (int kc = 0; kc < 12; kc++) {
    short8 ah[4], al[4], bh[2], bl[2];
#pragma unroll
    for (int mt = 0; mt < 4; mt++) {
      const size_t off = (size_t)(oc0 + mt * 16 + lm) * 384 + kc * 32 + lq * 8;
      ah[mt] = *reinterpret_cast<const short8*>(Wh + off);
      al[mt] = *reinterpret_cast<const short8*>(Wl + off);
    }
#pragma unroll
    for (int nt = 0; nt < 2; nt++) {
      const size_t idx = (size_t)((pt0 + nt) * 12 + kc) * 64 + lane;
      bh[nt] = Xh[idx];
      bl[nt] = Xl[idx];
    }
#pragma unroll
    for (int mt = 0; mt < 4; mt++)
#pragma unroll
      for (int nt = 0; nt < 2; nt++) {
        acc[mt][nt] = __builtin_amdgcn_mfma_f32_16x16x32_bf16(ah[mt], bh[nt], acc[mt][nt], 0, 0, 0);
        acc[mt][nt] = __builtin_amdgcn_mfma_f32_16x16x32_bf16(ah[mt], bl[nt], acc[mt][nt], 0, 0, 0);
        acc[mt][nt] = __builtin_amdgcn_mfma_f32_16x16x32_bf16(al[mt], bh[nt], acc[mt][nt], 0, 0, 0);
      }
  }
#pragma unroll
  for (int mt = 0; mt < 4; mt++)
#pragma unroll
    for (int nt = 0; nt < 2; nt++)
#pragma unroll
      for (int r = 0; r < 4; r++) {
        const int oc = oc0 + mt * 16 + lq * 4 + r;
        const int p = p0 + (wave * 2 + nt) * 16 + lm;
        Out[(size_t)oc * HW + p] = acc[mt][nt][r];
      }
}

// ---- depthwise 3x3 pad1, 384 channels (one qkv third) ----
__global__ __launch_bounds__(256) void dwconv3(const float* __restrict__ A,
                                               const float* __restrict__ wdw,
                                               float* __restrict__ Bq) {
  const int idx = blockIdx.x * 256 + threadIdx.x;
  const int x = idx & 127;
  const int y = (idx >> 7) & 127;
  const int ch = idx >> 14;
  float w[9];
#pragma unroll
  for (int t = 0; t < 9; t++) w[t] = wdw[ch * 9 + t];
  const float* Ap = A + (size_t)ch * HW;
  float acc = 0.f;
#pragma unroll
  for (int ky = 0; ky < 3; ky++) {
    const int yy = y + ky - 1;
    if (yy < 0 || yy > 127) continue;
#pragma unroll
    for (int kx = 0; kx < 3; kx++) {
      const int xx = x + kx - 1;
      if (xx < 0 || xx > 127) continue;
      acc += w[ky * 3 + kx] * Ap[yy * 128 + xx];
    }
  }
  Bq[idx] = acc;
}

// ---- per-channel 1/max(||row||,1e-12), rows 0..767 (q then k) ----
__global__ __launch_bounds__(256) void chan_norms(const float* __restrict__ Bq,
                                                  float* __restrict__ inv) {
  const int row = blockIdx.x;
  const size_t base = (size_t)row * HW;
  const int tid = threadIdx.x;
  float s = 0.f;
  for (int p = tid; p < HW; p += 256) {
    float v = Bq[base + p];
    s += v * v;
  }
  for (int o = 32; o; o >>= 1) s += __shfl_xor(s, o);
  __shared__ float red[4];
  if ((tid & 63) == 0) red[tid >> 6] = s;
  __syncthreads();
  if (tid == 0) {
    float t = red[0] + red[1] + red[2] + red[3];
    inv[row] = 1.f / fmaxf(sqrtf(t), 1e-12f);
  }
}

// ---- channel-attn partial logits: private slot per (chunk,head) ----
__global__ __launch_bounds__(256) void cattn_partial(const float* __restrict__ Bq,
                                                     float* __restrict__ part) {
  __shared__ __align__(16) float qs[48][65];
  __shared__ __align__(16) float ks2[48][65];
  const int tid = threadIdx.x;
  const int chunk = blockIdx.x, h = blockIdx.y;  // 16 chunks of 1024
  const int p0 = chunk * 1024;
  const int tx = tid & 15, ty = tid >> 4;
  const size_t qbase = (size_t)(h * CH) * HW;
  const size_t kbase = (size_t)(CDIM + h * CH) * HW;
  float acc[3][3] = {};
  for (int pp = 0; pp < 1024; pp += 64) {
    for (int s = tid; s < 48 * 64; s += 256) {
      int cc = s >> 6, pl = s & 63;
      qs[cc][pl] = Bq[qbase + (size_t)cc * HW + p0 + pp + pl];
      ks2[cc][pl] = Bq[kbase + (size_t)cc * HW + p0 + pp + pl];
    }
    __syncthreads();
#pragma unroll 4
    for (int pl = 0; pl < 64; pl++) {
      float qv[3], kv[3];
#pragma unroll
      for (int ii = 0; ii < 3; ii++) qv[ii] = qs[ty * 3 + ii][pl];
#pragma unroll
      for (int jj = 0; jj < 3; jj++) kv[jj] = ks2[tx * 3 + jj][pl];
#pragma unroll
      for (int ii = 0; ii < 3; ii++)
#pragma unroll
        for (int jj = 0; jj < 3; jj++) acc[ii][jj] += qv[ii] * kv[jj];
    }
    __syncthreads();
  }
  float* rp = part + (size_t)(h * 16 + chunk) * 2304;
#pragma unroll
  for (int ii = 0; ii < 3; ii++)
#pragma unroll
    for (int jj = 0; jj < 3; jj++)
      rp[(ty * 3 + ii) * 48 + tx * 3 + jj] = acc[ii][jj];
}

// ---- reduce 16 partials per head -> raw[h][48*48] ----
__global__ __launch_bounds__(256) void cattn_reduce(const float* __restrict__ part,
                                                    float* __restrict__ raw) {
  const int h = blockIdx.x;
  for (int idx = threadIdx.x; idx < 2304; idx += 256) {
    float s = 0.f;
#pragma unroll
    for (int c = 0; c < 16; c++) s += part[(size_t)(h * 16 + c) * 2304 + idx];
    raw[(size_t)h * 2304 + idx] = s;
  }
}

// ---- channel masked-softmax combine -> W48 ----
__global__ __launch_bounds__(64) void chan_softmax(
    const float* __restrict__ raw, const float* __restrict__ inv,
    const float* __restrict__ temp, const float* __restrict__ a1,
    const float* __restrict__ a2, const float* __restrict__ a3,
    const float* __restrict__ a4, float* __restrict__ W48) {
  const int blk = blockIdx.x;  // h*48 + i
  const int i = blk % 48;
  const int h = blk / 48;
  const int lane = threadIdx.x;
  const float t = temp[h];
  float a = -3.0e38f;
  if (lane < 48) {
    float r = raw[(size_t)blk * 48 + lane];
    a = t * inv[h * CH + i] * inv[CDIM + h * CH + lane] * r;
  }
  float m = a;
  for (int o = 32; o; o >>= 1) m = fmaxf(m, __shfl_xor(m, o));
  float e = (lane < 48) ? expf(a - m) : 0.f;
  int gt = 0;
  for (int j = 0; j < 48; j++) {
    float vj = __shfl(a, j);
    gt += (vj > a) ? 1 : 0;
  }
  const int ksel[4] = {24, 32, 36, 38};
  const float wts[4] = {a1[0], a2[0], a3[0], a4[0]};
  float coef = 0.f;
#pragma unroll
  for (int kk = 0; kk < 4; kk++) {
    float sel = (gt < ksel[kk]) ? e : 0.f;
    for (int o = 32; o; o >>= 1) sel += __shfl_xor(sel, o);
    if (gt < ksel[kk]) coef += wts[kk] / sel;
  }
  if (lane < 48) W48[(size_t)blk * 48 + lane] = e * coef;
}

// ---- channel out: Cbuf[h*48+i, p] = sum_j W48[h][i,j]*v[j,p] ----
__global__ __launch_bounds__(256) void cout_kernel(const float* __restrict__ W48,
                                                   const float* __restrict__ Bq,
                                                   float* __restrict__ Cbuf) {
  __shared__ __align__(16) float Wl[2304];
  const int tid = threadIdx.x;
  const int h = blockIdx.y;
  const float* wsrc = W48 + (size_t)h * 2304;
  for (int s = tid; s < 2304; s += 256) Wl[s] = wsrc[s];
  __syncthreads();
  const int p = blockIdx.x * 64 + (tid & 63);
  const int ig = tid >> 6;
  const float* vbase = Bq + (size_t)(2 * CDIM + h * CH) * HW + p;
  float acc[12] = {};
  for (int j0 = 0; j0 < 48; j0 += 4) {
    float vj[4];
#pragma unroll
    for (int q = 0; q < 4; q++) vj[q] = vbase[(size_t)(j0 + q) * HW];
#pragma unroll
    for (int ii = 0; ii < 12; ii++) {
      const float4 w4 = *reinterpret_cast<const float4*>(&Wl[(ig * 12 + ii) * 48 + j0]);
      acc[ii] += w4.x * vj[0] + w4.y * vj[1] + w4.z * vj[2] + w4.w * vj[3];
    }
  }
  float* obase = Cbuf + (size_t)(h * CH + ig * 12) * HW + p;
#pragma unroll
  for (int ii = 0; ii < 12; ii++) obase[(size_t)ii * HW] = acc[ii];
}

// ---- window attention, MFMA version ----
// Block = 1 window (64 tokens, 48 ch), 4 waves. Wave w owns output rows
// [16w,16w+16). QK^T and P·V on matrix cores (split-bf16 for fp32-level
// precision); bitonic top-k softmax per row unchanged.
__global__ __launch_bounds__(256, 4) void spatial_kernel(
    const float* __restrict__ Bq, const float* __restrict__ temp,
    const float* __restrict__ a1, const float* __restrict__ a2,
    const float* __restrict__ a3, const float* __restrict__ a4,
    float* __restrict__ Cbuf) {
  // LDS (bytes): region A [0,29120):
  //   phase 1-2: qRaw[64][49] f32 @0, kRaw[64][49] f32 @12544
  //   phase 3+ : S[64][65] f32 @0 (16640), vRawT[48][65] f32 @16640 (12480)
  //              (S region later reused as O[48][65] for the output transpose)
  // P bf16 [64][72] @29120 (9216); invQ[64] @38336; invK[64] @38592. Tot 38848.
  __shared__ __align__(16) char smem[38848];
  float* qRaw = (float*)smem;
  float* kRaw = (float*)(smem + 12544);
  float* S_lds = (float*)smem;
  float* vRawT = (float*)(smem + 16640);
  bf16* Pl = (bf16*)(smem + 29120);
  float* invQ = (float*)(smem + 38336);
  float* invK = (float*)(smem + 38592);

  const int wid = blockIdx.x;  // head*256 + wy*16 + wx
  const int wx = wid & 15, wy = (wid >> 4) & 15;
  const int head = wid >> 8;
  const int tid = threadIdx.x;
  const int lane = tid & 63, w = tid >> 6;
  const int lm = lane & 15, lq = lane >> 4;

  // phase 0: q,k windows -> raw LDS [tok][49] (49 odd => conflict-free writes)
  for (int s = tid; s < 2 * 3072; s += 256) {
    const int t = s / 3072;
    const int r = s % 3072;
    const int cc = r >> 6, n = r & 63;
    const int y = wy * 8 + (n >> 3), x = wx * 8 + (n & 7);
    const int chan = t * CDIM + head * CH + cc;
    (t ? kRaw : qRaw)[n * 49 + cc] = Bq[(size_t)chan * HW + y * 128 + x];
  }
  __syncthreads();  // barrier 1: raw q/k ready

  // V loads issued now (T14 async-stage): land in regs, LDS-written after
  // softmax so the HBM latency hides under compute.
  float vreg[12];
#pragma unroll
  for (int i = 0; i < 12; i++) {
    const int e = tid + i * 256;
    const int cc = e >> 6, n = e & 63;
    const int y = wy * 8 + (n >> 3), x = wx * 8 + (n & 7);
    vreg[i] = Bq[(size_t)(2 * CDIM + head * CH + cc) * HW + y * 128 + x];
  }

  // norms (threads 0..127); temperature folded into invQ
  if (tid < 128) {
    const int t = tid >> 6, n = tid & 63;
    const float* src = (t ? kRaw : qRaw) + n * 49;
    float ssum = 0.f;
    for (int cc = 0; cc < 48; cc++) {
      float v = src[cc];
      ssum += v * v;
    }
    const float iv = 1.f / fmaxf(sqrtf(ssum), 1e-12f);
    if (t) invK[n] = iv;
    else invQ[n] = iv * temp[head];
  }

  // Q A-frags (mt = w): Q[w*16+lm][ks*32+lq*8+j], split hi/lo
  short8 qh[2], ql[2];
#pragma unroll
  for (int ks = 0; ks < 2; ks++) {
    const int ch0 = ks * 32 + lq * 8;
    const float* qp = qRaw + (w * 16 + lm) * 49 + ch0;
#pragma unroll
    for (int j = 0; j < 8; j++) {
      const float v = (ch0 < 48) ? qp[j] : 0.f;
      const unsigned short hb = f2bf_bits(v);
      qh[ks][j] = (short)hb;
      ql[ks][j] = (short)f2bf_bits(v - bfbits2f(hb));
    }
  }
  // K B-frags per nt (scoped to limit VGPRs) + 24 MFMAs -> S in regs
  f32x4 sacc[4] = {};
#pragma unroll
  for (int nt = 0; nt < 4; nt++) {
    short8 kh[2], kl[2];
#pragma unroll
    for (int ks = 0; ks < 2; ks++) {
      const int ch0 = ks * 32 + lq * 8;
      const float* kp = kRaw + (nt * 16 + lm) * 49 + ch0;
#pragma unroll
      for (int j = 0; j < 8; j++) {
        const float v = (ch0 < 48) ? kp[j] : 0.f;
        const unsigned short hb = f2bf_bits(v);
        kh[ks][j] = (short)hb;
        kl[ks][j] = (short)f2bf_bits(v - bfbits2f(hb));
      }
    }
#pragma unroll
    for (int ks = 0; ks < 2; ks++) {
      sacc[nt] = __builtin_amdgcn_mfma_f32_16x16x32_bf16(qh[ks], kh[ks], sacc[nt], 0, 0, 0);
      sacc[nt] = __builtin_amdgcn_mfma_f32_16x16x32_bf16(qh[ks], kl[ks], sacc[nt], 0, 0, 0);
      sacc[nt] = __builtin_amdgcn_mfma_f32_16x16x32_bf16(ql[ks], kh[ks], sacc[nt], 0, 0, 0);
    }
  }
  __syncthreads();  // barrier 2: raw region free, inv ready

  // scaled S -> LDS. D layout: row = w*16+lq*4+r, col = nt*16+lm.
  float iq[4];
#pragma unroll
  for (int r = 0; r < 4; r++) iq[r] = invQ[w * 16 + lq * 4 + r];
#pragma unroll
  for (int nt = 0; nt < 4; nt++) {
    const float ik = invK[nt * 16 + lm];
#pragma unroll
    for (int r = 0; r < 4; r++)
      S_lds[(w * 16 + lq * 4 + r) * 65 + nt * 16 + lm] = sacc[nt][r] * iq[r] * ik;
  }

  // softmax + top-k per row (wave-local rows; S rows 16w..16w+15)
  const float wts[4] = {a1[0], a2[0], a3[0], a4[0]};
  const int ksel[4] = {32, 42, 48, 51};
#pragma unroll 4
  for (int rr = 0; rr < 16; rr++) {
    const int row = w * 16 + rr;
    const float a = S_lds[row * 65 + lane];
    float s = a;  // bitonic ascending sort across 64 lanes
#pragma unroll
    for (int k2 = 2; k2 <= 64; k2 <<= 1) {
#pragma unroll
      for (int j = k2 >> 1; j > 0; j >>= 1) {
        const float o = __shfl_xor(s, j);
        const bool up = ((lane & k2) == 0);
        const bool lower = ((lane & j) == 0);
        const float mn = fminf(s, o), mx = fmaxf(s, o);
        s = (lower == up) ? mn : mx;
      }
    }
    const float m = __shfl(s, 63);
    const float e = expf(a - m);
    float coef = 0.f;
#pragma unroll
    for (int kk = 0; kk < 4; kk++) {
      const float tk = __shfl(s, 64 - ksel[kk]);
      const bool keep = (a >= tk);
      float sel = keep ? e : 0.f;
      for (int o = 32; o; o >>= 1) sel += __shfl_xor(sel, o);
      if (keep) coef += wts[kk] / sel;
    }
    Pl[row * 72 + lane] = __float2bfloat16(e * coef);
  }

  // V regs -> vRawT[ch][65] (transposed by channel for b-frag reads)
#pragma unroll
  for (int i = 0; i < 12; i++) {
    const int e = tid + i * 256;
    vRawT[(e >> 6) * 65 + (e & 63)] = vreg[i];
  }
  __syncthreads();  // barrier 3: vRawT ready, all softmax done (S region free)

  // P·V: A = P (bf16, rows w*16..), B = V (split hi/lo). 12 MFMAs.
  short8 pa[2];
#pragma unroll
  for (int ks = 0; ks < 2; ks++)
    pa[ks] = *reinterpret_cast<const short8*>(&Pl[(w * 16 + lm) * 72 + ks * 32 + lq * 8]);
  f32x4 oacc[3] = {};
#pragma unroll
  for (int nt = 0; nt < 3; nt++) {
#pragma unroll
    for (int ks = 0; ks < 2; ks++) {
      short8 vh, vl;
      const float* vp = vRawT + (nt * 16 + lm) * 65 + ks * 32 + lq * 8;
#pragma unroll
      for (int j = 0; j < 8; j++) {
        const float v = vp[j];
        const unsigned short hb = f2bf_bits(v);
        vh[j] = (short)hb;
        vl[j] = (short)f2bf_bits(v - bfbits2f(hb));
      }
      oacc[nt] = __builtin_amdgcn_mfma_f32_16x16x32_bf16(pa[ks], vh, oacc[nt], 0, 0, 0);
      oacc[nt] = __builtin_amdgcn_mfma_f32_16x16x32_bf16(pa[ks], vl, oacc[nt], 0, 0, 0);
    }
  }

  // O -> LDS transposed [ch][tok] (reuse S region), then coalesced RMW out
#pragma unroll
  for (int nt = 0; nt < 3; nt++)
#pragma unroll
    for (int r = 0; r < 4; r++)
      S_lds[(nt * 16 + lm) * 65 + w * 16 + lq * 4 + r] = oacc[nt][r];
  __syncthreads();  // barrier 4: O ready

  const int y_out = wy * 8 + (wx >> 1);
  const int x0 = (wx & 1) * 64;
  for (int s = tid; s < 3072; s += 256) {
    const int cc = s >> 6, n = s & 63;
    const size_t idx = ((size_t)(head * CH + cc) * 128 + y_out) * 128 + x0 + n;
    Cbuf[idx] += S_lds[cc * 65 + n];
  }
}

// ---------------- launch ----------------
extern "C" void kernel_launch(void* const* d_in, const int* in_sizes, int n_in,
                              void* d_out, int out_size, void* d_ws, size_t ws_size,
                              hipStream_t stream) {
  const float* x = (const float*)d_in[0];
  const float* w_qkv = (const float*)d_in[1];
  const float* w_dw = (const float*)d_in[2];
  const float* w_proj = (const float*)d_in[3];
  const float* temp = (const float*)d_in[4];
  const float* a1 = (const float*)d_in[5];
  const float* a2 = (const float*)d_in[6];
  const float* a3 = (const float*)d_in[7];
  const float* a4 = (const float*)d_in[8];
  float* out = (float*)d_out;

  char* ws = (char*)d_ws;
  float* cattn_part = (float*)ws;
  float* raw = (float*)(ws + 1179648);
  float* W48 = (float*)(ws + 1253376);
  float* inv = (float*)(ws + 1327104);
  unsigned short* wqkv_h = (unsigned short*)(ws + 1330432);
  unsigned short* wqkv_l = (unsigned short*)(ws + 2215168);
  unsigned short* wproj_h = (unsigned short*)(ws + 3099904);
  unsigned short* wproj_l = (unsigned short*)(ws + 3394816);
  float* Bq = (float*)(ws + 3690496);
  short8* Xtgh = (short8*)(ws + 3690496 + (size_t)2 * CDIM * HW * 4);
  short8* Xtgl = (short8*)(ws + 3690496 + (size_t)2 * CDIM * HW * 4 + 12582912);
  short8* Ctgh = (short8*)(ws + 3690496);
  short8* Ctgl = (short8*)(ws + 3690496 + 12582912);

  decomp_w<<<(3 * CDIM * CDIM + 255) / 256, 256, 0, stream>>>(w_qkv, wqkv_h, wqkv_l,
                                                              3 * CDIM * CDIM);
  decomp_w<<<(CDIM * CDIM + 255) / 256, 256, 0, stream>>>(w_proj, wproj_h, wproj_l,
                                                          CDIM * CDIM);

  for (int b = 0; b < 2; b++) {
    const float* xb = x + (size_t)b * CDIM * HW;
    float* ob = out + (size_t)b * CDIM * HW;

    transpose_frag<<<3072, 256, 0, stream>>>(xb, Xtgh, Xtgl);
    for (int t = 0; t < 3; t++) {
      gemm_mfma<<<dim3(HW / 128, CDIM / 64), 256, 0, stream>>>(
          wqkv_h + (size_t)t * CDIM * CDIM, wqkv_l + (size_t)t * CDIM * CDIM,
          Xtgh, Xtgl, ob);
      dwconv3<<<(CDIM * HW) / 256, 256, 0, stream>>>(
          ob, w_dw + (size_t)t * CDIM * 9, Bq + (size_t)t * CDIM * HW);
    }

    chan_norms<<<2 * CDIM, 256, 0, stream>>>(Bq, inv);
    cattn_partial<<<dim3(16, NHEADS), 256, 0, stream>>>(Bq, cattn_part);
    cattn_reduce<<<NHEADS, 256, 0, stream>>>(cattn_part, raw);
    chan_softmax<<<NHEADS * 48, 64, 0, stream>>>(raw, inv, temp, a1, a2, a3, a4, W48);
    cout_kernel<<<dim3(HW / 64, NHEADS), 256, 0, stream>>>(W48, Bq, ob);
    spatial_kernel<<<NHEADS * 256, 256, 0, stream>>>(Bq, temp, a1, a2, a3, a4, ob);

    transpose_frag<<<3072, 256, 0, stream>>>(ob, Ctgh, Ctgl);
    gemm_mfma<<<dim3(HW / 128, CDIM / 64), 256, 0, stream>>>(wproj_h, wproj_l,
                                                             Ctgh, Ctgl, ob);
  }

  (void)in_sizes; (void)n_in; (void)out_size; (void)ws_size;
}

// Round 2
// 1081.092 us; speedup vs baseline: 1.2820x; 1.1179x over previous
//
#include <hip/hip_runtime.h>
#include <hip/hip_bf16.h>

// TKMDAttention on MI355X — round 9: spatial_kernel DS/VALU diet:
//  - softmax: DPP bitonic (quad_perm/row_ror for j=1,2,8) + suffix-scan of
//    exp over sorted values -> all 4 top-k denominators from one scan
//    (49 -> ~8 DS ops/row), fast rcp/exp (P is bf16-quantized anyway).
//  - cooperative K/V split-bf16 frag conversion in LDS (was 4x redundant/wave).
//  - XCD-aware window swizzle (adjacent wx windows share 64B lines -> co-XCD),
//    spatial pure-store; RMW moved to coalesced cout_kernel (runs after).
//  - gemm_mfma: bijective XCD swizzle so same-X-panel blocks share one L2.
// Shapes: b=2, C=384, H=W=128, heads=8, ch=48, crop=8, N=64.
// windowstoimg: token n of window (wy,wx) -> y = wy*8+(wx>>1), x = (wx&1)*64+n.
// top-k rule (tie-exact): keep i for k iff a_i >= k-th largest (ref "a >= kth").

#define HW 16384
#define CDIM 384
#define NHEADS 8
#define CH 48

typedef __hip_bfloat16 bf16;
typedef __attribute__((ext_vector_type(8))) short short8;
typedef __attribute__((ext_vector_type(4))) float f32x4;

static __device__ __forceinline__ unsigned short f2bf_bits(float v) {
  bf16 b = __float2bfloat16(v);
  return __builtin_bit_cast(unsigned short, b);
}
static __device__ __forceinline__ float bfbits2f(unsigned short u) {
  return __bfloat162float(__builtin_bit_cast(bf16, u));
}

// DPP move: returns x moved by CTRL (0-fill on invalid when bound_ctrl=true).
template <int CTRL>
static __device__ __forceinline__ float dppf(float x) {
  return __builtin_bit_cast(
      float, __builtin_amdgcn_update_dpp(0, __builtin_bit_cast(int, x), CTRL,
                                         0xF, 0xF, true));
}
// quad_perm(1,0,3,2)=0xB1 (xor1), quad_perm(2,3,0,1)=0x4E (xor2),
// row_ror:8=0x128 (xor8 within 16), row_shl:d=0x100+d (lane i <- i+d, 0-fill).

// ---- weight decompose: v = hi(bf16) + lo(bf16) ----
__global__ __launch_bounds__(256) void decomp_w(const float* __restrict__ src,
                                                unsigned short* __restrict__ h,
                                                unsigned short* __restrict__ l, int n) {
  int i = blockIdx.x * 256 + threadIdx.x;
  if (i >= n) return;
  float v = src[i];
  unsigned short hb = f2bf_bits(v);
  h[i] = hb;
  l[i] = f2bf_bits(v - bfbits2f(hb));
}

// ---- transpose src[384][16384] fp32 -> fragment-order bf16 hi/lo ----
__global__ __launch_bounds__(256) void transpose_frag(const float* __restrict__ src,
                                                      short8* __restrict__ dh,
                                                      short8* __restrict__ dl) {
  const int o = blockIdx.x * 256 + threadIdx.x;  // [0, 786432)
  const int ptile = o / 768;
  const int rem = o - ptile * 768;
  const int kc = rem >> 6, lane = rem & 63;
  const int p = ptile * 16 + (lane & 15);
  const int kb = kc * 32 + (lane >> 4) * 8;
  short8 hh, ll;
#pragma unroll
  for (int j = 0; j < 8; j++) {
    float v = src[(size_t)(kb + j) * HW + p];
    unsigned short hb = f2bf_bits(v);
    hh[j] = (short)hb;
    ll[j] = (short)f2bf_bits(v - bfbits2f(hb));
  }
  dh[o] = hh;
  dl[o] = ll;
}

// ---- split-bf16 MFMA GEMM: Out[oc][p] = sum_k W[oc][k] X[k][p], K=384 ----
// Grid is fixed (128, 6); XCD swizzle: the 6 oc-blocks sharing an X panel
// land on one XCD (16 panels * 192KB = 3MB < 4MB L2).
__global__ __launch_bounds__(256, 2) void gemm_mfma(const unsigned short* __restrict__ Wh,
                                                    const unsigned short* __restrict__ Wl,
                                                    const short8* __restrict__ Xh,
                                                    const short8* __restrict__ Xl,
                                                    float* __restrict__ Out) {
  const int tid = threadIdx.x;
  const int wave = tid >> 6, lane = tid & 63;
  const int lm = lane & 15, lq = lane >> 4;
  const int g = blockIdx.y * 128 + blockIdx.x;  // [0,768)
  const int xcd = g & 7, i = g >> 3;            // bijective remap
  const int bx = xcd * 16 + (i & 15);
  const int by = i >> 4;
  const int p0 = bx * 128;
  const int oc0 = by * 64;
  const int pt0 = bx * 8 + wave * 2;
  f32x4 acc[4][2] = {};
#pragma unroll
  for (int kc = 0; kc < 12; kc++) {
    short8 ah[4], al[4], bh[2], bl[2];
#pragma unroll
    for (int mt = 0; mt < 4; mt++) {
      const size_t off = (size_t)(oc0 + mt * 16 + lm) * 384 + kc * 32 + lq * 8;
      ah[mt] = *reinterpret_cast<const short8*>(Wh + off);
      al[mt] = *reinterpret_cast<const short8*>(Wl + off);
    }
#pragma unroll
    for (int nt = 0; nt < 2; nt++) {
      const size_t idx = (size_t)((pt0 + nt) * 12 + kc) * 64 + lane;
      bh[nt] = Xh[idx];
      bl[nt] = Xl[idx];
    }
#pragma unroll
    for (int mt = 0; mt < 4; mt++)
#pragma unroll
      for (int nt = 0; nt < 2; nt++) {
        acc[mt][nt] = __builtin_amdgcn_mfma_f32_16x16x32_bf16(ah[mt], bh[nt], acc[mt][nt], 0, 0, 0);
        acc[mt][nt] = __builtin_amdgcn_mfma_f32_16x16x32_bf16(ah[mt], bl[nt], acc[mt][nt], 0, 0, 0);
        acc[mt][nt] = __builtin_amdgcn_mfma_f32_16x16x32_bf16(al[mt], bh[nt], acc[mt][nt], 0, 0, 0);
      }
  }
#pragma unroll
  for (int mt = 0; mt < 4; mt++)
#pragma unroll
    for (int nt = 0; nt < 2; nt++)
#pragma unroll
      for (int r = 0; r < 4; r++) {
        const int oc = oc0 + mt * 16 + lq * 4 + r;
        const int p = p0 + (wave * 2 + nt) * 16 + lm;
        Out[(size_t)oc * HW + p] = acc[mt][nt][r];
      }
}

// ---- depthwise 3x3 pad1, 384 channels (one qkv third) ----
__global__ __launch_bounds__(256) void dwconv3(const float* __restrict__ A,
                                               const float* __restrict__ wdw,
                                               float* __restrict__ Bq) {
  const int idx = blockIdx.x * 256 + threadIdx.x;
  const int x = idx & 127;
  const int y = (idx >> 7) & 127;
  const int ch = idx >> 14;
  float w[9];
#pragma unroll
  for (int t = 0; t < 9; t++) w[t] = wdw[ch * 9 + t];
  const float* Ap = A + (size_t)ch * HW;
  float acc = 0.f;
#pragma unroll
  for (int ky = 0; ky < 3; ky++) {
    const int yy = y + ky - 1;
    if (yy < 0 || yy > 127) continue;
#pragma unroll
    for (int kx = 0; kx < 3; kx++) {
      const int xx = x + kx - 1;
      if (xx < 0 || xx > 127) continue;
      acc += w[ky * 3 + kx] * Ap[yy * 128 + xx];
    }
  }
  Bq[idx] = acc;
}

// ---- per-channel 1/max(||row||,1e-12), rows 0..767 (q then k) ----
__global__ __launch_bounds__(256) void chan_norms(const float* __restrict__ Bq,
                                                  float* __restrict__ inv) {
  const int row = blockIdx.x;
  const size_t base = (size_t)row * HW;
  const int tid = threadIdx.x;
  float s = 0.f;
  for (int p = tid; p < HW; p += 256) {
    float v = Bq[base + p];
    s += v * v;
  }
  for (int o = 32; o; o >>= 1) s += __shfl_xor(s, o);
  __shared__ float red[4];
  if ((tid & 63) == 0) red[tid >> 6] = s;
  __syncthreads();
  if (tid == 0) {
    float t = red[0] + red[1] + red[2] + red[3];
    inv[row] = 1.f / fmaxf(sqrtf(t), 1e-12f);
  }
}

// ---- channel-attn partial logits: private slot per (chunk,head) ----
__global__ __launch_bounds__(256) void cattn_partial(const float* __restrict__ Bq,
                                                     float* __restrict__ part) {
  __shared__ __align__(16) float qs[48][65];
  __shared__ __align__(16) float ks2[48][65];
  const int tid = threadIdx.x;
  const int chunk = blockIdx.x, h = blockIdx.y;  // 16 chunks of 1024
  const int p0 = chunk * 1024;
  const int tx = tid & 15, ty = tid >> 4;
  const size_t qbase = (size_t)(h * CH) * HW;
  const size_t kbase = (size_t)(CDIM + h * CH) * HW;
  float acc[3][3] = {};
  for (int pp = 0; pp < 1024; pp += 64) {
    for (int s = tid; s < 48 * 64; s += 256) {
      int cc = s >> 6, pl = s & 63;
      qs[cc][pl] = Bq[qbase + (size_t)cc * HW + p0 + pp + pl];
      ks2[cc][pl] = Bq[kbase + (size_t)cc * HW + p0 + pp + pl];
    }
    __syncthreads();
#pragma unroll 4
    for (int pl = 0; pl < 64; pl++) {
      float qv[3], kv[3];
#pragma unroll
      for (int ii = 0; ii < 3; ii++) qv[ii] = qs[ty * 3 + ii][pl];
#pragma unroll
      for (int jj = 0; jj < 3; jj++) kv[jj] = ks2[tx * 3 + jj][pl];
#pragma unroll
      for (int ii = 0; ii < 3; ii++)
#pragma unroll
        for (int jj = 0; jj < 3; jj++) acc[ii][jj] += qv[ii] * kv[jj];
    }
    __syncthreads();
  }
  float* rp = part + (size_t)(h * 16 + chunk) * 2304;
#pragma unroll
  for (int ii = 0; ii < 3; ii++)
#pragma unroll
    for (int jj = 0; jj < 3; jj++)
      rp[(ty * 3 + ii) * 48 + tx * 3 + jj] = acc[ii][jj];
}

// ---- reduce 16 partials per head -> raw[h][48*48] ----
__global__ __launch_bounds__(256) void cattn_reduce(const float* __restrict__ part,
                                                    float* __restrict__ raw) {
  const int h = blockIdx.x;
  for (int idx = threadIdx.x; idx < 2304; idx += 256) {
    float s = 0.f;
#pragma unroll
    for (int c = 0; c < 16; c++) s += part[(size_t)(h * 16 + c) * 2304 + idx];
    raw[(size_t)h * 2304 + idx] = s;
  }
}

// ---- channel masked-softmax combine -> W48 ----
__global__ __launch_bounds__(64) void chan_softmax(
    const float* __restrict__ raw, const float* __restrict__ inv,
    const float* __restrict__ temp, const float* __restrict__ a1,
    const float* __restrict__ a2, const float* __restrict__ a3,
    const float* __restrict__ a4, float* __restrict__ W48) {
  const int blk = blockIdx.x;  // h*48 + i
  const int i = blk % 48;
  const int h = blk / 48;
  const int lane = threadIdx.x;
  const float t = temp[h];
  float a = -3.0e38f;
  if (lane < 48) {
    float r = raw[(size_t)blk * 48 + lane];
    a = t * inv[h * CH + i] * inv[CDIM + h * CH + lane] * r;
  }
  float m = a;
  for (int o = 32; o; o >>= 1) m = fmaxf(m, __shfl_xor(m, o));
  float e = (lane < 48) ? expf(a - m) : 0.f;
  int gt = 0;
  for (int j = 0; j < 48; j++) {
    float vj = __shfl(a, j);
    gt += (vj > a) ? 1 : 0;
  }
  const int ksel[4] = {24, 32, 36, 38};
  const float wts[4] = {a1[0], a2[0], a3[0], a4[0]};
  float coef = 0.f;
#pragma unroll
  for (int kk = 0; kk < 4; kk++) {
    float sel = (gt < ksel[kk]) ? e : 0.f;
    for (int o = 32; o; o >>= 1) sel += __shfl_xor(sel, o);
    if (gt < ksel[kk]) coef += wts[kk] / sel;
  }
  if (lane < 48) W48[(size_t)blk * 48 + lane] = e * coef;
}

// ---- channel out (now RMW: adds onto spatial's output) ----
__global__ __launch_bounds__(256) void cout_kernel(const float* __restrict__ W48,
                                                   const float* __restrict__ Bq,
                                                   float* __restrict__ Cbuf) {
  __shared__ __align__(16) float Wl[2304];
  const int tid = threadIdx.x;
  const int h = blockIdx.y;
  const float* wsrc = W48 + (size_t)h * 2304;
  for (int s = tid; s < 2304; s += 256) Wl[s] = wsrc[s];
  __syncthreads();
  const int p = blockIdx.x * 64 + (tid & 63);
  const int ig = tid >> 6;
  const float* vbase = Bq + (size_t)(2 * CDIM + h * CH) * HW + p;
  float acc[12] = {};
  for (int j0 = 0; j0 < 48; j0 += 4) {
    float vj[4];
#pragma unroll
    for (int q = 0; q < 4; q++) vj[q] = vbase[(size_t)(j0 + q) * HW];
#pragma unroll
    for (int ii = 0; ii < 12; ii++) {
      const float4 w4 = *reinterpret_cast<const float4*>(&Wl[(ig * 12 + ii) * 48 + j0]);
      acc[ii] += w4.x * vj[0] + w4.y * vj[1] + w4.z * vj[2] + w4.w * vj[3];
    }
  }
  float* obase = Cbuf + (size_t)(h * CH + ig * 12) * HW + p;
#pragma unroll
  for (int ii = 0; ii < 12; ii++) obase[(size_t)ii * HW] += acc[ii];
}

// ---- cooperative split-bf16 frag converters (K and V) ----
static __device__ __forceinline__ void conv_frag_k(int f, const float* kRaw,
                                                   short8* KFh, short8* KFl) {
  int nt, ks, slot;
  if (f < 256) { nt = f >> 6; ks = 0; slot = f & 63; }
  else { const int g2 = f - 256; nt = g2 >> 5; ks = 1; slot = g2 & 31; }
  const int tok = nt * 16 + (slot & 15);
  const int ch0 = ks * 32 + (slot >> 4) * 8;
  const float* src = kRaw + tok * 49 + ch0;
  short8 hh, ll;
#pragma unroll
  for (int j = 0; j < 8; j++) {
    const float v = src[j];
    const unsigned short hb = f2bf_bits(v);
    hh[j] = (short)hb;
    ll[j] = (short)f2bf_bits(v - bfbits2f(hb));
  }
  KFh[f] = hh;
  KFl[f] = ll;
}
static __device__ __forceinline__ void conv_frag_v(int f, const float* vRawT,
                                                   short8* VFh, short8* VFl) {
  const int nt = f >> 7, rem = f & 127;
  const int ks = rem >> 6, slot = rem & 63;
  const int ch = nt * 16 + (slot & 15);
  const int t0 = ks * 32 + (slot >> 4) * 8;
  const float* src = vRawT + ch * 65 + t0;
  short8 hh, ll;
#pragma unroll
  for (int j = 0; j < 8; j++) {
    const float v = src[j];
    const unsigned short hb = f2bf_bits(v);
    hh[j] = (short)hb;
    ll[j] = (short)f2bf_bits(v - bfbits2f(hb));
  }
  VFh[f] = hh;
  VFl[f] = ll;
}

// ---- window attention, MFMA + DPP-softmax version ----
// Block = 1 window, 4 waves. Wave w owns output rows [16w,16w+16).
__global__ __launch_bounds__(256, 4) void spatial_kernel(
    const float* __restrict__ Bq, const float* __restrict__ temp,
    const float* __restrict__ a1, const float* __restrict__ a2,
    const float* __restrict__ a3, const float* __restrict__ a4,
    float* __restrict__ Cbuf) {
  // LDS regions (38848 B), lifetime-disjoint by barriers:
  //  [0,12544)      qRaw[64][49] f32     (b1..b2)
  //  [12544,25088)  kRaw[64][49] f32     (b1..b2)
  //  [25088,37376)  KFh/KFl short8[384]  (b2..b2.5)
  //  [0,16640)      S[64][65] f32        (post-QK..b3)
  //  [16640,29120)  vRawT[48][65] f32    (b2.5..b3.5), then O[48][65] (b3.5..)
  //  [0,12288)      VFh/VFl short8[384]  (b3..end)
  //  [29120,38336)  P bf16[64][72]       (b2.5..end)
  //  [38336,38848)  invQ[64], invK[64]
  __shared__ __align__(16) char smem[38848];
  float* qRaw = (float*)smem;
  float* kRaw = (float*)(smem + 12544);
  short8* KFh = (short8*)(smem + 25088);
  short8* KFl = (short8*)(smem + 31232);
  float* S_lds = (float*)smem;
  float* vRawT = (float*)(smem + 16640);
  short8* VFh = (short8*)smem;
  short8* VFl = (short8*)(smem + 6144);
  float* O_lds = (float*)(smem + 16640);
  bf16* Pl = (bf16*)(smem + 29120);
  float* invQ = (float*)(smem + 38336);
  float* invK = (float*)(smem + 38592);

  const int bid = blockIdx.x;
  const int wid = ((bid & 7) << 8) | (bid >> 3);  // XCD swizzle (2048=8*256)
  const int wx = wid & 15, wy = (wid >> 4) & 15;
  const int head = wid >> 8;
  const int tid = threadIdx.x;
  const int lane = tid & 63, w = tid >> 6;
  const int lm = lane & 15, lq = lane >> 4;
  const int ybase = wy * 8, xbase = wx * 8;
  const size_t hb = (size_t)(head * CH) * HW;

  // phase 0: q,k windows -> raw LDS (float4 global loads)
#pragma unroll
  for (int i = 0; i < 6; i++) {
    const int s4 = tid + i * 256;  // [0,1536)
    const int t = s4 >= 768;
    const int r4 = s4 - t * 768;
    const int cc = r4 >> 4, nq = r4 & 15;
    const int n = nq * 4;
    const int y = ybase + (n >> 3), x = xbase + (n & 7);
    const float4 v4 = *(const float4*)(Bq + (size_t)(t * CDIM) * HW + hb +
                                       (size_t)cc * HW + y * 128 + x);
    float* dst = (t ? kRaw : qRaw) + n * 49 + cc;
    dst[0] = v4.x; dst[49] = v4.y; dst[98] = v4.z; dst[147] = v4.w;
  }
  __syncthreads();  // b1

  // V loads (float4) issued early; land in regs, written to LDS post-b2.5
  float4 vv[3];
#pragma unroll
  for (int i = 0; i < 3; i++) {
    const int e4 = tid + i * 256;  // [0,768)
    const int cc = e4 >> 4, n = (e4 & 15) * 4;
    const int y = ybase + (n >> 3), x = xbase + (n & 7);
    vv[i] = *(const float4*)(Bq + (size_t)(2 * CDIM) * HW + hb +
                             (size_t)cc * HW + y * 128 + x);
  }

  // norms (threads 0..127); temperature folded into invQ
  if (tid < 128) {
    const int t = tid >> 6, n = tid & 63;
    const float* src = (t ? kRaw : qRaw) + n * 49;
    float ssum = 0.f;
#pragma unroll
    for (int cc = 0; cc < 48; cc++) { float v = src[cc]; ssum += v * v; }
    const float iv = 1.f / fmaxf(sqrtf(ssum), 1e-12f);
    if (t) invK[n] = iv; else invQ[n] = iv * temp[head];
  }

  // cooperative K -> split-bf16 frags (once per block, not per wave)
  conv_frag_k(tid, kRaw, KFh, KFl);
  if (tid < 128) conv_frag_k(256 + tid, kRaw, KFh, KFl);

  // Q A-frags (per-wave rows, not redundant): Q[w*16+lm][ks*32+lq*8+j]
  short8 qh[2], ql[2];
#pragma unroll
  for (int ks = 0; ks < 2; ks++) {
    const int ch0 = ks * 32 + lq * 8;
    const float* qp = qRaw + (w * 16 + lm) * 49 + ch0;
#pragma unroll
    for (int j = 0; j < 8; j++) {
      const float v = (ch0 < 48) ? qp[j] : 0.f;
      const unsigned short hbts = f2bf_bits(v);
      qh[ks][j] = (short)hbts;
      ql[ks][j] = (short)f2bf_bits(v - bfbits2f(hbts));
    }
  }
  __syncthreads();  // b2: KF + invs ready; raw regions dead

  // QK^T: 24 MFMAs (hi*hi + hi*lo + lo*hi per ks)
  f32x4 sacc[4] = {};
#pragma unroll
  for (int nt = 0; nt < 4; nt++) {
    const short8 kh0 = KFh[nt * 64 + lane];
    const short8 kl0 = KFl[nt * 64 + lane];
    sacc[nt] = __builtin_amdgcn_mfma_f32_16x16x32_bf16(qh[0], kh0, sacc[nt], 0, 0, 0);
    sacc[nt] = __builtin_amdgcn_mfma_f32_16x16x32_bf16(qh[0], kl0, sacc[nt], 0, 0, 0);
    sacc[nt] = __builtin_amdgcn_mfma_f32_16x16x32_bf16(ql[0], kh0, sacc[nt], 0, 0, 0);
    short8 kh1 = {0, 0, 0, 0, 0, 0, 0, 0}, kl1 = {0, 0, 0, 0, 0, 0, 0, 0};
    if (lane < 32) { kh1 = KFh[256 + nt * 32 + lane]; kl1 = KFl[256 + nt * 32 + lane]; }
    sacc[nt] = __builtin_amdgcn_mfma_f32_16x16x32_bf16(qh[1], kh1, sacc[nt], 0, 0, 0);
    sacc[nt] = __builtin_amdgcn_mfma_f32_16x16x32_bf16(qh[1], kl1, sacc[nt], 0, 0, 0);
    sacc[nt] = __builtin_amdgcn_mfma_f32_16x16x32_bf16(ql[1], kh1, sacc[nt], 0, 0, 0);
  }

  // scaled S -> LDS. D layout: row = w*16+lq*4+r, col = nt*16+lm.
  float iqv[4];
#pragma unroll
  for (int r = 0; r < 4; r++) iqv[r] = invQ[w * 16 + lq * 4 + r];
#pragma unroll
  for (int nt = 0; nt < 4; nt++) {
    const float ik = invK[nt * 16 + lm];
#pragma unroll
    for (int r = 0; r < 4; r++)
      S_lds[(w * 16 + lq * 4 + r) * 65 + nt * 16 + lm] = sacc[nt][r] * iqv[r] * ik;
  }
  __syncthreads();  // b2.5: all QK done; KF region dead

  // V regs -> vRawT[ch][65] (over kRaw tail + KF head)
#pragma unroll
  for (int i = 0; i < 3; i++) {
    const int e4 = tid + i * 256;
    const int cc = e4 >> 4, n = (e4 & 15) * 4;
    float* dst = vRawT + cc * 65 + n;
    dst[0] = vv[i].x; dst[1] = vv[i].y; dst[2] = vv[i].z; dst[3] = vv[i].w;
  }

  // softmax + top-k per row. Ascending bitonic sort (DPP for j=1,2,8),
  // then suffix-scan of exp over sorted values -> all 4 denominators.
  const float wts[4] = {a1[0], a2[0], a3[0], a4[0]};
  const int sidx[4] = {32, 22, 16, 13};  // 64-k for k in {32,42,48,51}
#pragma unroll 4
  for (int rr = 0; rr < 16; rr++) {
    const int row = w * 16 + rr;
    const float a = S_lds[row * 65 + lane];
    float s = a;
#pragma unroll
    for (int k2 = 2; k2 <= 64; k2 <<= 1) {
#pragma unroll
      for (int j = k2 >> 1; j > 0; j >>= 1) {
        float o;
        if (j == 1)      o = dppf<0xB1>(s);   // quad_perm xor1
        else if (j == 2) o = dppf<0x4E>(s);   // quad_perm xor2
        else if (j == 8) o = dppf<0x128>(s);  // row_ror:8 == xor8 in 16
        else             o = __shfl_xor(s, j);
        const bool up = ((lane & k2) == 0);
        const bool lower = ((lane & j) == 0);
        const float mn = fminf(s, o), mx = fmaxf(s, o);
        s = (lower == up) ? mn : mx;
      }
    }
    const float m = __shfl(s, 63);
    // inclusive suffix scan of exp(sorted - m): within-16 via DPP row_shl,
    // cross-row via 3 readlane row totals.
    float v = __expf(s - m);
    v += dppf<0x101>(v);  // row_shl:1
    v += dppf<0x102>(v);  // row_shl:2
    v += dppf<0x104>(v);  // row_shl:4
    v += dppf<0x108>(v);  // row_shl:8
    const float t1 = __shfl(v, 16), t2 = __shfl(v, 32), t3 = __shfl(v, 48);
    const float beyond =
        (lq == 0) ? (t1 + t2 + t3) : (lq == 1) ? (t2 + t3) : (lq == 2) ? t3 : 0.f;
    const float suf = v + beyond;  // suf[l] = sum_{j>=l} exp(s_j - m)
    const float e = __expf(a - m);
    float coef = 0.f;
#pragma unroll
    for (int kk = 0; kk < 4; kk++) {
      const float tk = __shfl(s, sidx[kk]);
      const float Sk = __shfl(suf, sidx[kk]);
      if (a >= tk) coef += wts[kk] * __builtin_amdgcn_rcpf(Sk);
    }
    Pl[row * 72 + lane] = __float2bfloat16(e * coef);
  }
  __syncthreads();  // b3: vRawT complete, S dead

  // cooperative V -> split-bf16 frags (over S region)
  conv_frag_v(tid, vRawT, VFh, VFl);
  if (tid < 128) conv_frag_v(256 + tid, vRawT, VFh, VFl);
  __syncthreads();  // b3.5: VF ready, vRawT dead

  // P.V: A = P (bf16), B = V (split hi/lo). 12 MFMAs.
  short8 pa[2];
#pragma unroll
  for (int ks = 0; ks < 2; ks++)
    pa[ks] = *reinterpret_cast<const short8*>(&Pl[(w * 16 + lm) * 72 + ks * 32 + lq * 8]);
  f32x4 oacc[3] = {};
#pragma unroll
  for (int nt = 0; nt < 3; nt++) {
#pragma unroll
    for (int ks = 0; ks < 2; ks++) {
      const short8 vh = VFh[nt * 128 + ks * 64 + lane];
      const short8 vl = VFl[nt * 128 + ks * 64 + lane];
      oacc[nt] = __builtin_amdgcn_mfma_f32_16x16x32_bf16(pa[ks], vh, oacc[nt], 0, 0, 0);
      oacc[nt] = __builtin_amdgcn_mfma_f32_16x16x32_bf16(pa[ks], vl, oacc[nt], 0, 0, 0);
    }
  }
  // O -> LDS transposed [ch][tok] (over vRawT region)
#pragma unroll
  for (int nt = 0; nt < 3; nt++)
#pragma unroll
    for (int r = 0; r < 4; r++)
      O_lds[(nt * 16 + lm) * 65 + w * 16 + lq * 4 + r] = oacc[nt][r];
  __syncthreads();  // b4

  // pure store (cout_kernel adds afterwards), float4-coalesced
  const int y_out = wy * 8 + (wx >> 1);
  const int x0 = (wx & 1) * 64;
#pragma unroll
  for (int i = 0; i < 3; i++) {
    const int s4 = tid + i * 256;
    const int cc = s4 >> 4, n = (s4 & 15) * 4;
    const float* op = O_lds + cc * 65 + n;
    const float4 o4 = {op[0], op[1], op[2], op[3]};
    *(float4*)(Cbuf + ((size_t)(head * CH + cc) * 128 + y_out) * 128 + x0 + n) = o4;
  }
}

// ---------------- launch ----------------
extern "C" void kernel_launch(void* const* d_in, const int* in_sizes, int n_in,
                              void* d_out, int out_size, void* d_ws, size_t ws_size,
                              hipStream_t stream) {
  const float* x = (const float*)d_in[0];
  const float* w_qkv = (const float*)d_in[1];
  const float* w_dw = (const float*)d_in[2];
  const float* w_proj = (const float*)d_in[3];
  const float* temp = (const float*)d_in[4];
  const float* a1 = (const float*)d_in[5];
  const float* a2 = (const float*)d_in[6];
  const float* a3 = (const float*)d_in[7];
  const float* a4 = (const float*)d_in[8];
  float* out = (float*)d_out;

  char* ws = (char*)d_ws;
  float* cattn_part = (float*)ws;
  float* raw = (float*)(ws + 1179648);
  float* W48 = (float*)(ws + 1253376);
  float* inv = (float*)(ws + 1327104);
  unsigned short* wqkv_h = (unsigned short*)(ws + 1330432);
  unsigned short* wqkv_l = (unsigned short*)(ws + 2215168);
  unsigned short* wproj_h = (unsigned short*)(ws + 3099904);
  unsigned short* wproj_l = (unsigned short*)(ws + 3394816);
  float* Bq = (float*)(ws + 3690496);
  short8* Xtgh = (short8*)(ws + 3690496 + (size_t)2 * CDIM * HW * 4);
  short8* Xtgl = (short8*)(ws + 3690496 + (size_t)2 * CDIM * HW * 4 + 12582912);
  short8* Ctgh = (short8*)(ws + 3690496);
  short8* Ctgl = (short8*)(ws + 3690496 + 12582912);

  decomp_w<<<(3 * CDIM * CDIM + 255) / 256, 256, 0, stream>>>(w_qkv, wqkv_h, wqkv_l,
                                                              3 * CDIM * CDIM);
  decomp_w<<<(CDIM * CDIM + 255) / 256, 256, 0, stream>>>(w_proj, wproj_h, wproj_l,
                                                          CDIM * CDIM);

  for (int b = 0; b < 2; b++) {
    const float* xb = x + (size_t)b * CDIM * HW;
    float* ob = out + (size_t)b * CDIM * HW;

    transpose_frag<<<3072, 256, 0, stream>>>(xb, Xtgh, Xtgl);
    for (int t = 0; t < 3; t++) {
      gemm_mfma<<<dim3(HW / 128, CDIM / 64), 256, 0, stream>>>(
          wqkv_h + (size_t)t * CDIM * CDIM, wqkv_l + (size_t)t * CDIM * CDIM,
          Xtgh, Xtgl, ob);
      dwconv3<<<(CDIM * HW) / 256, 256, 0, stream>>>(
          ob, w_dw + (size_t)t * CDIM * 9, Bq + (size_t)t * CDIM * HW);
    }

    chan_norms<<<2 * CDIM, 256, 0, stream>>>(Bq, inv);
    cattn_partial<<<dim3(16, NHEADS), 256, 0, stream>>>(Bq, cattn_part);
    cattn_reduce<<<NHEADS, 256, 0, stream>>>(cattn_part, raw);
    chan_softmax<<<NHEADS * 48, 64, 0, stream>>>(raw, inv, temp, a1, a2, a3, a4, W48);
    spatial_kernel<<<NHEADS * 256, 256, 0, stream>>>(Bq, temp, a1, a2, a3, a4, ob);
    cout_kernel<<<dim3(HW / 64, NHEADS), 256, 0, stream>>>(W48, Bq, ob);

    transpose_frag<<<3072, 256, 0, stream>>>(ob, Ctgh, Ctgl);
    gemm_mfma<<<dim3(HW / 128, CDIM / 64), 256, 0, stream>>>(wproj_h, wproj_l,
                                                             Ctgh, Ctgl, ob);
  }

  (void)in_sizes; (void)n_in; (void)out_size; (void)ws_size;
}

// Round 3
// 921.543 us; speedup vs baseline: 1.5039x; 1.1731x over previous
//
#include <hip/hip_runtime.h>
#include <hip/hip_bf16.h>

// TKMDAttention on MI355X — round 10: cattn parallelism fix.
//  - cattn_partial: NCHUNK 16 -> 128 (grid 1024 blocks, was 128 => 5% occupancy,
//    94us). Channel-major LDS [48][132], float4 staging + float4 dot along
//    pixels. Predicted ~13us.
//  - cattn_reduce folded into chan_softmax (2 fewer launches, no raw buffer).
//  - everything else = round 9 (spatial MFMA+DPP softmax, XCD swizzles).
// Shapes: b=2, C=384, H=W=128, heads=8, ch=48, crop=8, N=64.
// windowstoimg: token n of window (wy,wx) -> y = wy*8+(wx>>1), x = (wx&1)*64+n.
// top-k rule (tie-exact): keep i for k iff a_i >= k-th largest (ref "a >= kth").

#define HW 16384
#define CDIM 384
#define NHEADS 8
#define CH 48
#define NCHUNK 128

typedef __hip_bfloat16 bf16;
typedef __attribute__((ext_vector_type(8))) short short8;
typedef __attribute__((ext_vector_type(4))) float f32x4;

static __device__ __forceinline__ unsigned short f2bf_bits(float v) {
  bf16 b = __float2bfloat16(v);
  return __builtin_bit_cast(unsigned short, b);
}
static __device__ __forceinline__ float bfbits2f(unsigned short u) {
  return __bfloat162float(__builtin_bit_cast(bf16, u));
}

// DPP move: returns x moved by CTRL (0-fill on invalid when bound_ctrl=true).
template <int CTRL>
static __device__ __forceinline__ float dppf(float x) {
  return __builtin_bit_cast(
      float, __builtin_amdgcn_update_dpp(0, __builtin_bit_cast(int, x), CTRL,
                                         0xF, 0xF, true));
}
// quad_perm(1,0,3,2)=0xB1 (xor1), quad_perm(2,3,0,1)=0x4E (xor2),
// row_ror:8=0x128 (xor8 within 16), row_shl:d=0x100+d (lane i <- i+d, 0-fill).

// ---- weight decompose: v = hi(bf16) + lo(bf16) ----
__global__ __launch_bounds__(256) void decomp_w(const float* __restrict__ src,
                                                unsigned short* __restrict__ h,
                                                unsigned short* __restrict__ l, int n) {
  int i = blockIdx.x * 256 + threadIdx.x;
  if (i >= n) return;
  float v = src[i];
  unsigned short hb = f2bf_bits(v);
  h[i] = hb;
  l[i] = f2bf_bits(v - bfbits2f(hb));
}

// ---- transpose src[384][16384] fp32 -> fragment-order bf16 hi/lo ----
__global__ __launch_bounds__(256) void transpose_frag(const float* __restrict__ src,
                                                      short8* __restrict__ dh,
                                                      short8* __restrict__ dl) {
  const int o = blockIdx.x * 256 + threadIdx.x;  // [0, 786432)
  const int ptile = o / 768;
  const int rem = o - ptile * 768;
  const int kc = rem >> 6, lane = rem & 63;
  const int p = ptile * 16 + (lane & 15);
  const int kb = kc * 32 + (lane >> 4) * 8;
  short8 hh, ll;
#pragma unroll
  for (int j = 0; j < 8; j++) {
    float v = src[(size_t)(kb + j) * HW + p];
    unsigned short hb = f2bf_bits(v);
    hh[j] = (short)hb;
    ll[j] = (short)f2bf_bits(v - bfbits2f(hb));
  }
  dh[o] = hh;
  dl[o] = ll;
}

// ---- split-bf16 MFMA GEMM: Out[oc][p] = sum_k W[oc][k] X[k][p], K=384 ----
// Grid is fixed (128, 6); XCD swizzle: the 6 oc-blocks sharing an X panel
// land on one XCD (16 panels * 192KB = 3MB < 4MB L2).
__global__ __launch_bounds__(256, 2) void gemm_mfma(const unsigned short* __restrict__ Wh,
                                                    const unsigned short* __restrict__ Wl,
                                                    const short8* __restrict__ Xh,
                                                    const short8* __restrict__ Xl,
                                                    float* __restrict__ Out) {
  const int tid = threadIdx.x;
  const int wave = tid >> 6, lane = tid & 63;
  const int lm = lane & 15, lq = lane >> 4;
  const int g = blockIdx.y * 128 + blockIdx.x;  // [0,768)
  const int xcd = g & 7, i = g >> 3;            // bijective remap
  const int bx = xcd * 16 + (i & 15);
  const int by = i >> 4;
  const int p0 = bx * 128;
  const int oc0 = by * 64;
  const int pt0 = bx * 8 + wave * 2;
  f32x4 acc[4][2] = {};
#pragma unroll
  for (int kc = 0; kc < 12; kc++) {
    short8 ah[4], al[4], bh[2], bl[2];
#pragma unroll
    for (int mt = 0; mt < 4; mt++) {
      const size_t off = (size_t)(oc0 + mt * 16 + lm) * 384 + kc * 32 + lq * 8;
      ah[mt] = *reinterpret_cast<const short8*>(Wh + off);
      al[mt] = *reinterpret_cast<const short8*>(Wl + off);
    }
#pragma unroll
    for (int nt = 0; nt < 2; nt++) {
      const size_t idx = (size_t)((pt0 + nt) * 12 + kc) * 64 + lane;
      bh[nt] = Xh[idx];
      bl[nt] = Xl[idx];
    }
#pragma unroll
    for (int mt = 0; mt < 4; mt++)
#pragma unroll
      for (int nt = 0; nt < 2; nt++) {
        acc[mt][nt] = __builtin_amdgcn_mfma_f32_16x16x32_bf16(ah[mt], bh[nt], acc[mt][nt], 0, 0, 0);
        acc[mt][nt] = __builtin_amdgcn_mfma_f32_16x16x32_bf16(ah[mt], bl[nt], acc[mt][nt], 0, 0, 0);
        acc[mt][nt] = __builtin_amdgcn_mfma_f32_16x16x32_bf16(al[mt], bh[nt], acc[mt][nt], 0, 0, 0);
      }
  }
#pragma unroll
  for (int mt = 0; mt < 4; mt++)
#pragma unroll
    for (int nt = 0; nt < 2; nt++)
#pragma unroll
      for (int r = 0; r < 4; r++) {
        const int oc = oc0 + mt * 16 + lq * 4 + r;
        const int p = p0 + (wave * 2 + nt) * 16 + lm;
        Out[(size_t)oc * HW + p] = acc[mt][nt][r];
      }
}

// ---- depthwise 3x3 pad1, 384 channels (one qkv third) ----
__global__ __launch_bounds__(256) void dwconv3(const float* __restrict__ A,
                                               const float* __restrict__ wdw,
                                               float* __restrict__ Bq) {
  const int idx = blockIdx.x * 256 + threadIdx.x;
  const int x = idx & 127;
  const int y = (idx >> 7) & 127;
  const int ch = idx >> 14;
  float w[9];
#pragma unroll
  for (int t = 0; t < 9; t++) w[t] = wdw[ch * 9 + t];
  const float* Ap = A + (size_t)ch * HW;
  float acc = 0.f;
#pragma unroll
  for (int ky = 0; ky < 3; ky++) {
    const int yy = y + ky - 1;
    if (yy < 0 || yy > 127) continue;
#pragma unroll
    for (int kx = 0; kx < 3; kx++) {
      const int xx = x + kx - 1;
      if (xx < 0 || xx > 127) continue;
      acc += w[ky * 3 + kx] * Ap[yy * 128 + xx];
    }
  }
  Bq[idx] = acc;
}

// ---- per-channel 1/max(||row||,1e-12), rows 0..767 (q then k) ----
__global__ __launch_bounds__(256) void chan_norms(const float* __restrict__ Bq,
                                                  float* __restrict__ inv) {
  const int row = blockIdx.x;
  const size_t base = (size_t)row * HW;
  const int tid = threadIdx.x;
  float s = 0.f;
  for (int p = tid; p < HW; p += 256) {
    float v = Bq[base + p];
    s += v * v;
  }
  for (int o = 32; o; o >>= 1) s += __shfl_xor(s, o);
  __shared__ float red[4];
  if ((tid & 63) == 0) red[tid >> 6] = s;
  __syncthreads();
  if (tid == 0) {
    float t = red[0] + red[1] + red[2] + red[3];
    inv[row] = 1.f / fmaxf(sqrtf(t), 1e-12f);
  }
}

// ---- channel-attn partials: 128 chunks x 8 heads, 128 pixels per block ----
// LDS channel-major [48][132]: float4 staging writes conflict-free, compute
// reads 2-way max (free). 3x3 outputs/thread, float4 dot along pixels.
__global__ __launch_bounds__(256, 3) void cattn_partial(const float* __restrict__ Bq,
                                                        float* __restrict__ part) {
  __shared__ __align__(16) float qs[48 * 132];
  __shared__ __align__(16) float ks2[48 * 132];
  const int tid = threadIdx.x;
  const int chunk = blockIdx.x, h = blockIdx.y;
  const int p0 = chunk * 128;
  // stage q,k planes: 2*48*32 = 3072 float4
#pragma unroll
  for (int i = 0; i < 12; i++) {
    const int s4 = tid + i * 256;
    const int t = s4 >= 1536;
    const int r4 = s4 - t * 1536;
    const int cc = r4 >> 5;
    const int px = (r4 & 31) << 2;
    const float4 v4 = *(const float4*)(Bq + (size_t)(t * CDIM + h * CH + cc) * HW + p0 + px);
    *(float4*)((t ? ks2 : qs) + cc * 132 + px) = v4;
  }
  __syncthreads();
  const int tx = tid & 15, ty = tid >> 4;
  const float* qb = qs + (ty * 3) * 132;
  const float* kb = ks2 + (tx * 3) * 132;
  float acc[3][3] = {};
  for (int pl = 0; pl < 128; pl += 4) {
    float4 qv[3], kv[3];
#pragma unroll
    for (int ii = 0; ii < 3; ii++) qv[ii] = *(const float4*)(qb + ii * 132 + pl);
#pragma unroll
    for (int jj = 0; jj < 3; jj++) kv[jj] = *(const float4*)(kb + jj * 132 + pl);
#pragma unroll
    for (int ii = 0; ii < 3; ii++)
#pragma unroll
      for (int jj = 0; jj < 3; jj++)
        acc[ii][jj] += qv[ii].x * kv[jj].x + qv[ii].y * kv[jj].y +
                       qv[ii].z * kv[jj].z + qv[ii].w * kv[jj].w;
  }
  float* rp = part + (size_t)(h * NCHUNK + chunk) * 2304;
#pragma unroll
  for (int ii = 0; ii < 3; ii++)
#pragma unroll
    for (int jj = 0; jj < 3; jj++)
      rp[(ty * 3 + ii) * 48 + tx * 3 + jj] = acc[ii][jj];
}

// ---- channel masked-softmax combine (reduce folded in) -> W48 ----
__global__ __launch_bounds__(64) void chan_softmax(
    const float* __restrict__ part, const float* __restrict__ inv,
    const float* __restrict__ temp, const float* __restrict__ a1,
    const float* __restrict__ a2, const float* __restrict__ a3,
    const float* __restrict__ a4, float* __restrict__ W48) {
  const int blk = blockIdx.x;  // h*48 + i
  const int i = blk % 48;
  const int h = blk / 48;
  const int lane = threadIdx.x;
  const float t = temp[h];
  float a = -3.0e38f;
  if (lane < 48) {
    const float* pp = part + (size_t)h * NCHUNK * 2304 + i * 48 + lane;
    float r = 0.f;
#pragma unroll 8
    for (int c = 0; c < NCHUNK; c++) r += pp[(size_t)c * 2304];
    a = t * inv[h * CH + i] * inv[CDIM + h * CH + lane] * r;
  }
  float m = a;
  for (int o = 32; o; o >>= 1) m = fmaxf(m, __shfl_xor(m, o));
  float e = (lane < 48) ? expf(a - m) : 0.f;
  int gt = 0;
  for (int j = 0; j < 48; j++) {
    float vj = __shfl(a, j);
    gt += (vj > a) ? 1 : 0;
  }
  const int ksel[4] = {24, 32, 36, 38};
  const float wts[4] = {a1[0], a2[0], a3[0], a4[0]};
  float coef = 0.f;
#pragma unroll
  for (int kk = 0; kk < 4; kk++) {
    float sel = (gt < ksel[kk]) ? e : 0.f;
    for (int o = 32; o; o >>= 1) sel += __shfl_xor(sel, o);
    if (gt < ksel[kk]) coef += wts[kk] / sel;
  }
  if (lane < 48) W48[(size_t)blk * 48 + lane] = e * coef;
}

// ---- channel out (RMW: adds onto spatial's output) ----
__global__ __launch_bounds__(256) void cout_kernel(const float* __restrict__ W48,
                                                   const float* __restrict__ Bq,
                                                   float* __restrict__ Cbuf) {
  __shared__ __align__(16) float Wl[2304];
  const int tid = threadIdx.x;
  const int h = blockIdx.y;
  const float* wsrc = W48 + (size_t)h * 2304;
  for (int s = tid; s < 2304; s += 256) Wl[s] = wsrc[s];
  __syncthreads();
  const int p = blockIdx.x * 64 + (tid & 63);
  const int ig = tid >> 6;
  const float* vbase = Bq + (size_t)(2 * CDIM + h * CH) * HW + p;
  float acc[12] = {};
  for (int j0 = 0; j0 < 48; j0 += 4) {
    float vj[4];
#pragma unroll
    for (int q = 0; q < 4; q++) vj[q] = vbase[(size_t)(j0 + q) * HW];
#pragma unroll
    for (int ii = 0; ii < 12; ii++) {
      const float4 w4 = *reinterpret_cast<const float4*>(&Wl[(ig * 12 + ii) * 48 + j0]);
      acc[ii] += w4.x * vj[0] + w4.y * vj[1] + w4.z * vj[2] + w4.w * vj[3];
    }
  }
  float* obase = Cbuf + (size_t)(h * CH + ig * 12) * HW + p;
#pragma unroll
  for (int ii = 0; ii < 12; ii++) obase[(size_t)ii * HW] += acc[ii];
}

// ---- cooperative split-bf16 frag converters (K and V) ----
static __device__ __forceinline__ void conv_frag_k(int f, const float* kRaw,
                                                   short8* KFh, short8* KFl) {
  int nt, ks, slot;
  if (f < 256) { nt = f >> 6; ks = 0; slot = f & 63; }
  else { const int g2 = f - 256; nt = g2 >> 5; ks = 1; slot = g2 & 31; }
  const int tok = nt * 16 + (slot & 15);
  const int ch0 = ks * 32 + (slot >> 4) * 8;
  const float* src = kRaw + tok * 49 + ch0;
  short8 hh, ll;
#pragma unroll
  for (int j = 0; j < 8; j++) {
    const float v = src[j];
    const unsigned short hb = f2bf_bits(v);
    hh[j] = (short)hb;
    ll[j] = (short)f2bf_bits(v - bfbits2f(hb));
  }
  KFh[f] = hh;
  KFl[f] = ll;
}
static __device__ __forceinline__ void conv_frag_v(int f, const float* vRawT,
                                                   short8* VFh, short8* VFl) {
  const int nt = f >> 7, rem = f & 127;
  const int ks = rem >> 6, slot = rem & 63;
  const int ch = nt * 16 + (slot & 15);
  const int t0 = ks * 32 + (slot >> 4) * 8;
  const float* src = vRawT + ch * 65 + t0;
  short8 hh, ll;
#pragma unroll
  for (int j = 0; j < 8; j++) {
    const float v = src[j];
    const unsigned short hb = f2bf_bits(v);
    hh[j] = (short)hb;
    ll[j] = (short)f2bf_bits(v - bfbits2f(hb));
  }
  VFh[f] = hh;
  VFl[f] = ll;
}

// ---- window attention, MFMA + DPP-softmax version ----
// Block = 1 window, 4 waves. Wave w owns output rows [16w,16w+16).
__global__ __launch_bounds__(256, 4) void spatial_kernel(
    const float* __restrict__ Bq, const float* __restrict__ temp,
    const float* __restrict__ a1, const float* __restrict__ a2,
    const float* __restrict__ a3, const float* __restrict__ a4,
    float* __restrict__ Cbuf) {
  // LDS regions (38848 B), lifetime-disjoint by barriers:
  //  [0,12544)      qRaw[64][49] f32     (b1..b2)
  //  [12544,25088)  kRaw[64][49] f32     (b1..b2)
  //  [25088,37376)  KFh/KFl short8[384]  (b2..b2.5)
  //  [0,16640)      S[64][65] f32        (post-QK..b3)
  //  [16640,29120)  vRawT[48][65] f32    (b2.5..b3.5), then O[48][65] (b3.5..)
  //  [0,12288)      VFh/VFl short8[384]  (b3..end)
  //  [29120,38336)  P bf16[64][72]       (b2.5..end)
  //  [38336,38848)  invQ[64], invK[64]
  __shared__ __align__(16) char smem[38848];
  float* qRaw = (float*)smem;
  float* kRaw = (float*)(smem + 12544);
  short8* KFh = (short8*)(smem + 25088);
  short8* KFl = (short8*)(smem + 31232);
  float* S_lds = (float*)smem;
  float* vRawT = (float*)(smem + 16640);
  short8* VFh = (short8*)smem;
  short8* VFl = (short8*)(smem + 6144);
  float* O_lds = (float*)(smem + 16640);
  bf16* Pl = (bf16*)(smem + 29120);
  float* invQ = (float*)(smem + 38336);
  float* invK = (float*)(smem + 38592);

  const int bid = blockIdx.x;
  const int wid = ((bid & 7) << 8) | (bid >> 3);  // XCD swizzle (2048=8*256)
  const int wx = wid & 15, wy = (wid >> 4) & 15;
  const int head = wid >> 8;
  const int tid = threadIdx.x;
  const int lane = tid & 63, w = tid >> 6;
  const int lm = lane & 15, lq = lane >> 4;
  const int ybase = wy * 8, xbase = wx * 8;
  const size_t hb = (size_t)(head * CH) * HW;

  // phase 0: q,k windows -> raw LDS (float4 global loads)
#pragma unroll
  for (int i = 0; i < 6; i++) {
    const int s4 = tid + i * 256;  // [0,1536)
    const int t = s4 >= 768;
    const int r4 = s4 - t * 768;
    const int cc = r4 >> 4, nq = r4 & 15;
    const int n = nq * 4;
    const int y = ybase + (n >> 3), x = xbase + (n & 7);
    const float4 v4 = *(const float4*)(Bq + (size_t)(t * CDIM) * HW + hb +
                                       (size_t)cc * HW + y * 128 + x);
    float* dst = (t ? kRaw : qRaw) + n * 49 + cc;
    dst[0] = v4.x; dst[49] = v4.y; dst[98] = v4.z; dst[147] = v4.w;
  }
  __syncthreads();  // b1

  // V loads (float4) issued early; land in regs, written to LDS post-b2.5
  float4 vv[3];
#pragma unroll
  for (int i = 0; i < 3; i++) {
    const int e4 = tid + i * 256;  // [0,768)
    const int cc = e4 >> 4, n = (e4 & 15) * 4;
    const int y = ybase + (n >> 3), x = xbase + (n & 7);
    vv[i] = *(const float4*)(Bq + (size_t)(2 * CDIM) * HW + hb +
                             (size_t)cc * HW + y * 128 + x);
  }

  // norms (threads 0..127); temperature folded into invQ
  if (tid < 128) {
    const int t = tid >> 6, n = tid & 63;
    const float* src = (t ? kRaw : qRaw) + n * 49;
    float ssum = 0.f;
#pragma unroll
    for (int cc = 0; cc < 48; cc++) { float v = src[cc]; ssum += v * v; }
    const float iv = 1.f / fmaxf(sqrtf(ssum), 1e-12f);
    if (t) invK[n] = iv; else invQ[n] = iv * temp[head];
  }

  // cooperative K -> split-bf16 frags (once per block, not per wave)
  conv_frag_k(tid, kRaw, KFh, KFl);
  if (tid < 128) conv_frag_k(256 + tid, kRaw, KFh, KFl);

  // Q A-frags (per-wave rows, not redundant): Q[w*16+lm][ks*32+lq*8+j]
  short8 qh[2], ql[2];
#pragma unroll
  for (int ks = 0; ks < 2; ks++) {
    const int ch0 = ks * 32 + lq * 8;
    const float* qp = qRaw + (w * 16 + lm) * 49 + ch0;
#pragma unroll
    for (int j = 0; j < 8; j++) {
      const float v = (ch0 < 48) ? qp[j] : 0.f;
      const unsigned short hbts = f2bf_bits(v);
      qh[ks][j] = (short)hbts;
      ql[ks][j] = (short)f2bf_bits(v - bfbits2f(hbts));
    }
  }
  __syncthreads();  // b2: KF + invs ready; raw regions dead

  // QK^T: 24 MFMAs (hi*hi + hi*lo + lo*hi per ks)
  f32x4 sacc[4] = {};
#pragma unroll
  for (int nt = 0; nt < 4; nt++) {
    const short8 kh0 = KFh[nt * 64 + lane];
    const short8 kl0 = KFl[nt * 64 + lane];
    sacc[nt] = __builtin_amdgcn_mfma_f32_16x16x32_bf16(qh[0], kh0, sacc[nt], 0, 0, 0);
    sacc[nt] = __builtin_amdgcn_mfma_f32_16x16x32_bf16(qh[0], kl0, sacc[nt], 0, 0, 0);
    sacc[nt] = __builtin_amdgcn_mfma_f32_16x16x32_bf16(ql[0], kh0, sacc[nt], 0, 0, 0);
    short8 kh1 = {0, 0, 0, 0, 0, 0, 0, 0}, kl1 = {0, 0, 0, 0, 0, 0, 0, 0};
    if (lane < 32) { kh1 = KFh[256 + nt * 32 + lane]; kl1 = KFl[256 + nt * 32 + lane]; }
    sacc[nt] = __builtin_amdgcn_mfma_f32_16x16x32_bf16(qh[1], kh1, sacc[nt], 0, 0, 0);
    sacc[nt] = __builtin_amdgcn_mfma_f32_16x16x32_bf16(qh[1], kl1, sacc[nt], 0, 0, 0);
    sacc[nt] = __builtin_amdgcn_mfma_f32_16x16x32_bf16(ql[1], kh1, sacc[nt], 0, 0, 0);
  }

  // scaled S -> LDS. D layout: row = w*16+lq*4+r, col = nt*16+lm.
  float iqv[4];
#pragma unroll
  for (int r = 0; r < 4; r++) iqv[r] = invQ[w * 16 + lq * 4 + r];
#pragma unroll
  for (int nt = 0; nt < 4; nt++) {
    const float ik = invK[nt * 16 + lm];
#pragma unroll
    for (int r = 0; r < 4; r++)
      S_lds[(w * 16 + lq * 4 + r) * 65 + nt * 16 + lm] = sacc[nt][r] * iqv[r] * ik;
  }
  __syncthreads();  // b2.5: all QK done; KF region dead

  // V regs -> vRawT[ch][65] (over kRaw tail + KF head)
#pragma unroll
  for (int i = 0; i < 3; i++) {
    const int e4 = tid + i * 256;
    const int cc = e4 >> 4, n = (e4 & 15) * 4;
    float* dst = vRawT + cc * 65 + n;
    dst[0] = vv[i].x; dst[1] = vv[i].y; dst[2] = vv[i].z; dst[3] = vv[i].w;
  }

  // softmax + top-k per row. Ascending bitonic sort (DPP for j=1,2,8),
  // then suffix-scan of exp over sorted values -> all 4 denominators.
  const float wts[4] = {a1[0], a2[0], a3[0], a4[0]};
  const int sidx[4] = {32, 22, 16, 13};  // 64-k for k in {32,42,48,51}
#pragma unroll 4
  for (int rr = 0; rr < 16; rr++) {
    const int row = w * 16 + rr;
    const float a = S_lds[row * 65 + lane];
    float s = a;
#pragma unroll
    for (int k2 = 2; k2 <= 64; k2 <<= 1) {
#pragma unroll
      for (int j = k2 >> 1; j > 0; j >>= 1) {
        float o;
        if (j == 1)      o = dppf<0xB1>(s);   // quad_perm xor1
        else if (j == 2) o = dppf<0x4E>(s);   // quad_perm xor2
        else if (j == 8) o = dppf<0x128>(s);  // row_ror:8 == xor8 in 16
        else             o = __shfl_xor(s, j);
        const bool up = ((lane & k2) == 0);
        const bool lower = ((lane & j) == 0);
        const float mn = fminf(s, o), mx = fmaxf(s, o);
        s = (lower == up) ? mn : mx;
      }
    }
    const float m = __shfl(s, 63);
    // inclusive suffix scan of exp(sorted - m): within-16 via DPP row_shl,
    // cross-row via 3 readlane row totals.
    float v = __expf(s - m);
    v += dppf<0x101>(v);  // row_shl:1
    v += dppf<0x102>(v);  // row_shl:2
    v += dppf<0x104>(v);  // row_shl:4
    v += dppf<0x108>(v);  // row_shl:8
    const float t1 = __shfl(v, 16), t2 = __shfl(v, 32), t3 = __shfl(v, 48);
    const float beyond =
        (lq == 0) ? (t1 + t2 + t3) : (lq == 1) ? (t2 + t3) : (lq == 2) ? t3 : 0.f;
    const float suf = v + beyond;  // suf[l] = sum_{j>=l} exp(s_j - m)
    const float e = __expf(a - m);
    float coef = 0.f;
#pragma unroll
    for (int kk = 0; kk < 4; kk++) {
      const float tk = __shfl(s, sidx[kk]);
      const float Sk = __shfl(suf, sidx[kk]);
      if (a >= tk) coef += wts[kk] * __builtin_amdgcn_rcpf(Sk);
    }
    Pl[row * 72 + lane] = __float2bfloat16(e * coef);
  }
  __syncthreads();  // b3: vRawT complete, S dead

  // cooperative V -> split-bf16 frags (over S region)
  conv_frag_v(tid, vRawT, VFh, VFl);
  if (tid < 128) conv_frag_v(256 + tid, vRawT, VFh, VFl);
  __syncthreads();  // b3.5: VF ready, vRawT dead

  // P.V: A = P (bf16), B = V (split hi/lo). 12 MFMAs.
  short8 pa[2];
#pragma unroll
  for (int ks = 0; ks < 2; ks++)
    pa[ks] = *reinterpret_cast<const short8*>(&Pl[(w * 16 + lm) * 72 + ks * 32 + lq * 8]);
  f32x4 oacc[3] = {};
#pragma unroll
  for (int nt = 0; nt < 3; nt++) {
#pragma unroll
    for (int ks = 0; ks < 2; ks++) {
      const short8 vh = VFh[nt * 128 + ks * 64 + lane];
      const short8 vl = VFl[nt * 128 + ks * 64 + lane];
      oacc[nt] = __builtin_amdgcn_mfma_f32_16x16x32_bf16(pa[ks], vh, oacc[nt], 0, 0, 0);
      oacc[nt] = __builtin_amdgcn_mfma_f32_16x16x32_bf16(pa[ks], vl, oacc[nt], 0, 0, 0);
    }
  }
  // O -> LDS transposed [ch][tok] (over vRawT region)
#pragma unroll
  for (int nt = 0; nt < 3; nt++)
#pragma unroll
    for (int r = 0; r < 4; r++)
      O_lds[(nt * 16 + lm) * 65 + w * 16 + lq * 4 + r] = oacc[nt][r];
  __syncthreads();  // b4

  // pure store (cout_kernel adds afterwards), float4-coalesced
  const int y_out = wy * 8 + (wx >> 1);
  const int x0 = (wx & 1) * 64;
#pragma unroll
  for (int i = 0; i < 3; i++) {
    const int s4 = tid + i * 256;
    const int cc = s4 >> 4, n = (s4 & 15) * 4;
    const float* op = O_lds + cc * 65 + n;
    const float4 o4 = {op[0], op[1], op[2], op[3]};
    *(float4*)(Cbuf + ((size_t)(head * CH + cc) * 128 + y_out) * 128 + x0 + n) = o4;
  }
}

// ---------------- launch ----------------
extern "C" void kernel_launch(void* const* d_in, const int* in_sizes, int n_in,
                              void* d_out, int out_size, void* d_ws, size_t ws_size,
                              hipStream_t stream) {
  const float* x = (const float*)d_in[0];
  const float* w_qkv = (const float*)d_in[1];
  const float* w_dw = (const float*)d_in[2];
  const float* w_proj = (const float*)d_in[3];
  const float* temp = (const float*)d_in[4];
  const float* a1 = (const float*)d_in[5];
  const float* a2 = (const float*)d_in[6];
  const float* a3 = (const float*)d_in[7];
  const float* a4 = (const float*)d_in[8];
  float* out = (float*)d_out;

  // ws layout (bytes):
  //   [0,         9437184)  cattn_part f32 (128*8*2304)
  //   [9437184,   9510912)  W48 f32
  //   [9510912,   9513984)  inv f32 (768)
  //   [9513984,  10398720)  wqkv_h bf16 bits (1152x384)
  //   [10398720, 11283456)  wqkv_l
  //   [11283456, 11578368)  wproj_h (384x384)
  //   [11578368, 11873280)  wproj_l
  //   [11873280, 87370752)  Bq f32 (1152x16384) = 75.5 MB
  //     Xtg hi/lo in Bq v-third during qkv phase; Ctg hi/lo in q-third for proj.
  // Peak 87.4 MB (<= proven 89.4 MB).
  char* ws = (char*)d_ws;
  float* cattn_part = (float*)ws;
  float* W48 = (float*)(ws + 9437184);
  float* inv = (float*)(ws + 9510912);
  unsigned short* wqkv_h = (unsigned short*)(ws + 9513984);
  unsigned short* wqkv_l = (unsigned short*)(ws + 10398720);
  unsigned short* wproj_h = (unsigned short*)(ws + 11283456);
  unsigned short* wproj_l = (unsigned short*)(ws + 11578368);
  float* Bq = (float*)(ws + 11873280);
  short8* Xtgh = (short8*)(ws + 11873280 + (size_t)2 * CDIM * HW * 4);
  short8* Xtgl = (short8*)(ws + 11873280 + (size_t)2 * CDIM * HW * 4 + 12582912);
  short8* Ctgh = (short8*)(ws + 11873280);
  short8* Ctgl = (short8*)(ws + 11873280 + 12582912);

  decomp_w<<<(3 * CDIM * CDIM + 255) / 256, 256, 0, stream>>>(w_qkv, wqkv_h, wqkv_l,
                                                              3 * CDIM * CDIM);
  decomp_w<<<(CDIM * CDIM + 255) / 256, 256, 0, stream>>>(w_proj, wproj_h, wproj_l,
                                                          CDIM * CDIM);

  for (int b = 0; b < 2; b++) {
    const float* xb = x + (size_t)b * CDIM * HW;
    float* ob = out + (size_t)b * CDIM * HW;

    transpose_frag<<<3072, 256, 0, stream>>>(xb, Xtgh, Xtgl);
    for (int t = 0; t < 3; t++) {
      gemm_mfma<<<dim3(HW / 128, CDIM / 64), 256, 0, stream>>>(
          wqkv_h + (size_t)t * CDIM * CDIM, wqkv_l + (size_t)t * CDIM * CDIM,
          Xtgh, Xtgl, ob);
      dwconv3<<<(CDIM * HW) / 256, 256, 0, stream>>>(
          ob, w_dw + (size_t)t * CDIM * 9, Bq + (size_t)t * CDIM * HW);
    }

    chan_norms<<<2 * CDIM, 256, 0, stream>>>(Bq, inv);
    cattn_partial<<<dim3(NCHUNK, NHEADS), 256, 0, stream>>>(Bq, cattn_part);
    chan_softmax<<<NHEADS * 48, 64, 0, stream>>>(cattn_part, inv, temp, a1, a2, a3, a4, W48);
    spatial_kernel<<<NHEADS * 256, 256, 0, stream>>>(Bq, temp, a1, a2, a3, a4, ob);
    cout_kernel<<<dim3(HW / 64, NHEADS), 256, 0, stream>>>(W48, Bq, ob);

    transpose_frag<<<3072, 256, 0, stream>>>(ob, Ctgh, Ctgl);
    gemm_mfma<<<dim3(HW / 128, CDIM / 64), 256, 0, stream>>>(wproj_h, wproj_l,
                                                             Ctgh, Ctgl, ob);
  }

  (void)in_sizes; (void)n_in; (void)out_size; (void)ws_size;
}

// Round 4
// 804.517 us; speedup vs baseline: 1.7227x; 1.1455x over previous
//
#include <hip/hip_runtime.h>
#include <hip/hip_bf16.h>

// TKMDAttention on MI355X — round 11:
//  - gemm_mfma: launch_bounds (256,2) -> (256,4): 12-deep direct-global K-loop
//    was latency-bound at 2 waves/SIMD.
//  - dwconv3: 4 pixels/thread, float4 loads (was scalar 1 px/thread).
//  - chan_norms: float4 loads.
//  - spatial: V converted to split-bf16 in regs and written straight into
//    frag-layout VT[48][72] ushort (kills vRawT round-trip, conv_frag_v pass
//    and one barrier). LDS re-laid out, peak 40192 B (4 blocks/CU).
// Shapes: b=2, C=384, H=W=128, heads=8, ch=48, crop=8, N=64.
// windowstoimg: token n of window (wy,wx) -> y = wy*8+(wx>>1), x = (wx&1)*64+n.
// top-k rule (tie-exact): keep i for k iff a_i >= k-th largest (ref "a >= kth").

#define HW 16384
#define CDIM 384
#define NHEADS 8
#define CH 48
#define NCHUNK 128

typedef __hip_bfloat16 bf16;
typedef __attribute__((ext_vector_type(8))) short short8;
typedef __attribute__((ext_vector_type(4))) float f32x4;

static __device__ __forceinline__ unsigned short f2bf_bits(float v) {
  bf16 b = __float2bfloat16(v);
  return __builtin_bit_cast(unsigned short, b);
}
static __device__ __forceinline__ float bfbits2f(unsigned short u) {
  return __bfloat162float(__builtin_bit_cast(bf16, u));
}

// DPP move: returns x moved by CTRL (0-fill on invalid when bound_ctrl=true).
template <int CTRL>
static __device__ __forceinline__ float dppf(float x) {
  return __builtin_bit_cast(
      float, __builtin_amdgcn_update_dpp(0, __builtin_bit_cast(int, x), CTRL,
                                         0xF, 0xF, true));
}
// quad_perm(1,0,3,2)=0xB1 (xor1), quad_perm(2,3,0,1)=0x4E (xor2),
// row_ror:8=0x128 (xor8 within 16), row_shl:d=0x100+d (lane i <- i+d, 0-fill).

// ---- weight decompose: v = hi(bf16) + lo(bf16) ----
__global__ __launch_bounds__(256) void decomp_w(const float* __restrict__ src,
                                                unsigned short* __restrict__ h,
                                                unsigned short* __restrict__ l, int n) {
  int i = blockIdx.x * 256 + threadIdx.x;
  if (i >= n) return;
  float v = src[i];
  unsigned short hb = f2bf_bits(v);
  h[i] = hb;
  l[i] = f2bf_bits(v - bfbits2f(hb));
}

// ---- transpose src[384][16384] fp32 -> fragment-order bf16 hi/lo ----
__global__ __launch_bounds__(256) void transpose_frag(const float* __restrict__ src,
                                                      short8* __restrict__ dh,
                                                      short8* __restrict__ dl) {
  const int o = blockIdx.x * 256 + threadIdx.x;  // [0, 786432)
  const int ptile = o / 768;
  const int rem = o - ptile * 768;
  const int kc = rem >> 6, lane = rem & 63;
  const int p = ptile * 16 + (lane & 15);
  const int kb = kc * 32 + (lane >> 4) * 8;
  short8 hh, ll;
#pragma unroll
  for (int j = 0; j < 8; j++) {
    float v = src[(size_t)(kb + j) * HW + p];
    unsigned short hb = f2bf_bits(v);
    hh[j] = (short)hb;
    ll[j] = (short)f2bf_bits(v - bfbits2f(hb));
  }
  dh[o] = hh;
  dl[o] = ll;
}

// ---- split-bf16 MFMA GEMM: Out[oc][p] = sum_k W[oc][k] X[k][p], K=384 ----
// Grid is fixed (128, 6); XCD swizzle: the 6 oc-blocks sharing an X panel
// land on one XCD (16 panels * 192KB = 3MB < 4MB L2).
__global__ __launch_bounds__(256, 4) void gemm_mfma(const unsigned short* __restrict__ Wh,
                                                    const unsigned short* __restrict__ Wl,
                                                    const short8* __restrict__ Xh,
                                                    const short8* __restrict__ Xl,
                                                    float* __restrict__ Out) {
  const int tid = threadIdx.x;
  const int wave = tid >> 6, lane = tid & 63;
  const int lm = lane & 15, lq = lane >> 4;
  const int g = blockIdx.y * 128 + blockIdx.x;  // [0,768)
  const int xcd = g & 7, i = g >> 3;            // bijective remap
  const int bx = xcd * 16 + (i & 15);
  const int by = i >> 4;
  const int p0 = bx * 128;
  const int oc0 = by * 64;
  const int pt0 = bx * 8 + wave * 2;
  f32x4 acc[4][2] = {};
#pragma unroll
  for (int kc = 0; kc < 12; kc++) {
    short8 ah[4], al[4], bh[2], bl[2];
#pragma unroll
    for (int mt = 0; mt < 4; mt++) {
      const size_t off = (size_t)(oc0 + mt * 16 + lm) * 384 + kc * 32 + lq * 8;
      ah[mt] = *reinterpret_cast<const short8*>(Wh + off);
      al[mt] = *reinterpret_cast<const short8*>(Wl + off);
    }
#pragma unroll
    for (int nt = 0; nt < 2; nt++) {
      const size_t idx = (size_t)((pt0 + nt) * 12 + kc) * 64 + lane;
      bh[nt] = Xh[idx];
      bl[nt] = Xl[idx];
    }
#pragma unroll
    for (int mt = 0; mt < 4; mt++)
#pragma unroll
      for (int nt = 0; nt < 2; nt++) {
        acc[mt][nt] = __builtin_amdgcn_mfma_f32_16x16x32_bf16(ah[mt], bh[nt], acc[mt][nt], 0, 0, 0);
        acc[mt][nt] = __builtin_amdgcn_mfma_f32_16x16x32_bf16(ah[mt], bl[nt], acc[mt][nt], 0, 0, 0);
        acc[mt][nt] = __builtin_amdgcn_mfma_f32_16x16x32_bf16(al[mt], bh[nt], acc[mt][nt], 0, 0, 0);
      }
  }
#pragma unroll
  for (int mt = 0; mt < 4; mt++)
#pragma unroll
    for (int nt = 0; nt < 2; nt++)
#pragma unroll
      for (int r = 0; r < 4; r++) {
        const int oc = oc0 + mt * 16 + lq * 4 + r;
        const int p = p0 + (wave * 2 + nt) * 16 + lm;
        Out[(size_t)oc * HW + p] = acc[mt][nt][r];
      }
}

// ---- depthwise 3x3 pad1, 384 channels; 4 pixels/thread, float4 loads ----
__global__ __launch_bounds__(256) void dwconv3(const float* __restrict__ A,
                                               const float* __restrict__ wdw,
                                               float* __restrict__ Bq) {
  const int e = blockIdx.x * 256 + threadIdx.x;  // [0, 384*128*32)
  const int x4 = e & 31;
  const int y = (e >> 5) & 127;
  const int ch = e >> 12;
  const int x0 = x4 << 2;
  float w[9];
#pragma unroll
  for (int t = 0; t < 9; t++) w[t] = wdw[ch * 9 + t];
  const float* Ap = A + (size_t)ch * HW;
  float4 acc = {0.f, 0.f, 0.f, 0.f};
#pragma unroll
  for (int ky = 0; ky < 3; ky++) {
    const int yy = y + ky - 1;
    if (yy < 0 || yy > 127) continue;
    const float* row = Ap + yy * 128;
    const float4 c = *(const float4*)(row + x0);
    const float l = (x4 == 0) ? 0.f : row[x0 - 1];
    const float r = (x4 == 31) ? 0.f : row[x0 + 4];
    const float w0 = w[ky * 3], w1 = w[ky * 3 + 1], w2 = w[ky * 3 + 2];
    acc.x += w0 * l + w1 * c.x + w2 * c.y;
    acc.y += w0 * c.x + w1 * c.y + w2 * c.z;
    acc.z += w0 * c.y + w1 * c.z + w2 * c.w;
    acc.w += w0 * c.z + w1 * c.w + w2 * r;
  }
  *(float4*)(Bq + (size_t)e * 4) = acc;
}

// ---- per-channel 1/max(||row||,1e-12), rows 0..767 (q then k) ----
__global__ __launch_bounds__(256) void chan_norms(const float* __restrict__ Bq,
                                                  float* __restrict__ inv) {
  const int row = blockIdx.x;
  const float4* base = (const float4*)(Bq + (size_t)row * HW);
  const int tid = threadIdx.x;
  float s = 0.f;
  for (int p = tid; p < HW / 4; p += 256) {
    const float4 v = base[p];
    s += v.x * v.x + v.y * v.y + v.z * v.z + v.w * v.w;
  }
  for (int o = 32; o; o >>= 1) s += __shfl_xor(s, o);
  __shared__ float red[4];
  if ((tid & 63) == 0) red[tid >> 6] = s;
  __syncthreads();
  if (tid == 0) {
    float t = red[0] + red[1] + red[2] + red[3];
    inv[row] = 1.f / fmaxf(sqrtf(t), 1e-12f);
  }
}

// ---- channel-attn partials: 128 chunks x 8 heads, 128 pixels per block ----
__global__ __launch_bounds__(256, 3) void cattn_partial(const float* __restrict__ Bq,
                                                        float* __restrict__ part) {
  __shared__ __align__(16) float qs[48 * 132];
  __shared__ __align__(16) float ks2[48 * 132];
  const int tid = threadIdx.x;
  const int chunk = blockIdx.x, h = blockIdx.y;
  const int p0 = chunk * 128;
#pragma unroll
  for (int i = 0; i < 12; i++) {
    const int s4 = tid + i * 256;
    const int t = s4 >= 1536;
    const int r4 = s4 - t * 1536;
    const int cc = r4 >> 5;
    const int px = (r4 & 31) << 2;
    const float4 v4 = *(const float4*)(Bq + (size_t)(t * CDIM + h * CH + cc) * HW + p0 + px);
    *(float4*)((t ? ks2 : qs) + cc * 132 + px) = v4;
  }
  __syncthreads();
  const int tx = tid & 15, ty = tid >> 4;
  const float* qb = qs + (ty * 3) * 132;
  const float* kb = ks2 + (tx * 3) * 132;
  float acc[3][3] = {};
  for (int pl = 0; pl < 128; pl += 4) {
    float4 qv[3], kv[3];
#pragma unroll
    for (int ii = 0; ii < 3; ii++) qv[ii] = *(const float4*)(qb + ii * 132 + pl);
#pragma unroll
    for (int jj = 0; jj < 3; jj++) kv[jj] = *(const float4*)(kb + jj * 132 + pl);
#pragma unroll
    for (int ii = 0; ii < 3; ii++)
#pragma unroll
      for (int jj = 0; jj < 3; jj++)
        acc[ii][jj] += qv[ii].x * kv[jj].x + qv[ii].y * kv[jj].y +
                       qv[ii].z * kv[jj].z + qv[ii].w * kv[jj].w;
  }
  float* rp = part + (size_t)(h * NCHUNK + chunk) * 2304;
#pragma unroll
  for (int ii = 0; ii < 3; ii++)
#pragma unroll
    for (int jj = 0; jj < 3; jj++)
      rp[(ty * 3 + ii) * 48 + tx * 3 + jj] = acc[ii][jj];
}

// ---- channel masked-softmax combine (reduce folded in) -> W48 ----
__global__ __launch_bounds__(64) void chan_softmax(
    const float* __restrict__ part, const float* __restrict__ inv,
    const float* __restrict__ temp, const float* __restrict__ a1,
    const float* __restrict__ a2, const float* __restrict__ a3,
    const float* __restrict__ a4, float* __restrict__ W48) {
  const int blk = blockIdx.x;  // h*48 + i
  const int i = blk % 48;
  const int h = blk / 48;
  const int lane = threadIdx.x;
  const float t = temp[h];
  float a = -3.0e38f;
  if (lane < 48) {
    const float* pp = part + (size_t)h * NCHUNK * 2304 + i * 48 + lane;
    float r = 0.f;
#pragma unroll 8
    for (int c = 0; c < NCHUNK; c++) r += pp[(size_t)c * 2304];
    a = t * inv[h * CH + i] * inv[CDIM + h * CH + lane] * r;
  }
  float m = a;
  for (int o = 32; o; o >>= 1) m = fmaxf(m, __shfl_xor(m, o));
  float e = (lane < 48) ? expf(a - m) : 0.f;
  int gt = 0;
  for (int j = 0; j < 48; j++) {
    float vj = __shfl(a, j);
    gt += (vj > a) ? 1 : 0;
  }
  const int ksel[4] = {24, 32, 36, 38};
  const float wts[4] = {a1[0], a2[0], a3[0], a4[0]};
  float coef = 0.f;
#pragma unroll
  for (int kk = 0; kk < 4; kk++) {
    float sel = (gt < ksel[kk]) ? e : 0.f;
    for (int o = 32; o; o >>= 1) sel += __shfl_xor(sel, o);
    if (gt < ksel[kk]) coef += wts[kk] / sel;
  }
  if (lane < 48) W48[(size_t)blk * 48 + lane] = e * coef;
}

// ---- channel out (RMW: adds onto spatial's output) ----
__global__ __launch_bounds__(256) void cout_kernel(const float* __restrict__ W48,
                                                   const float* __restrict__ Bq,
                                                   float* __restrict__ Cbuf) {
  __shared__ __align__(16) float Wl[2304];
  const int tid = threadIdx.x;
  const int h = blockIdx.y;
  const float* wsrc = W48 + (size_t)h * 2304;
  for (int s = tid; s < 2304; s += 256) Wl[s] = wsrc[s];
  __syncthreads();
  const int p = blockIdx.x * 64 + (tid & 63);
  const int ig = tid >> 6;
  const float* vbase = Bq + (size_t)(2 * CDIM + h * CH) * HW + p;
  float acc[12] = {};
  for (int j0 = 0; j0 < 48; j0 += 4) {
    float vj[4];
#pragma unroll
    for (int q = 0; q < 4; q++) vj[q] = vbase[(size_t)(j0 + q) * HW];
#pragma unroll
    for (int ii = 0; ii < 12; ii++) {
      const float4 w4 = *reinterpret_cast<const float4*>(&Wl[(ig * 12 + ii) * 48 + j0]);
      acc[ii] += w4.x * vj[0] + w4.y * vj[1] + w4.z * vj[2] + w4.w * vj[3];
    }
  }
  float* obase = Cbuf + (size_t)(h * CH + ig * 12) * HW + p;
#pragma unroll
  for (int ii = 0; ii < 12; ii++) obase[(size_t)ii * HW] += acc[ii];
}

// ---- cooperative split-bf16 frag converter (K) ----
static __device__ __forceinline__ void conv_frag_k(int f, const float* kRaw,
                                                   short8* KFh, short8* KFl) {
  int nt, ks, slot;
  if (f < 256) { nt = f >> 6; ks = 0; slot = f & 63; }
  else { const int g2 = f - 256; nt = g2 >> 5; ks = 1; slot = g2 & 31; }
  const int tok = nt * 16 + (slot & 15);
  const int ch0 = ks * 32 + (slot >> 4) * 8;
  const float* src = kRaw + tok * 49 + ch0;
  short8 hh, ll;
#pragma unroll
  for (int j = 0; j < 8; j++) {
    const float v = src[j];
    const unsigned short hb = f2bf_bits(v);
    hh[j] = (short)hb;
    ll[j] = (short)f2bf_bits(v - bfbits2f(hb));
  }
  KFh[f] = hh;
  KFl[f] = ll;
}

// ---- window attention, MFMA + DPP-softmax, direct-bf16 V ----
// Block = 1 window, 4 waves. Wave w owns output rows [16w,16w+16).
__global__ __launch_bounds__(256, 4) void spatial_kernel(
    const float* __restrict__ Bq, const float* __restrict__ temp,
    const float* __restrict__ a1, const float* __restrict__ a2,
    const float* __restrict__ a3, const float* __restrict__ a4,
    float* __restrict__ Cbuf) {
  // LDS regions (40192 B), lifetime-disjoint by barriers:
  //  [0,12544)      qRaw[64][49] f32     (b1..b2)
  //  [12544,25088)  kRaw[64][49] f32     (b1..b2)
  //  [25088,37376)  KFh/KFl short8[384]  (pre-b2..b2.5)
  //  [0,16640)      S[64][65] f32        (post-b2..softmax; reads pre-b3)
  //  [16640,30464)  VTh/VTl ush[48][72]  (post-b2.5..PV)
  //  [30464,39680)  P bf16[64][72]       (softmax..pa; over KF tail, dead)
  //  [0,12480)      O[48][65] f32        (post-b3)
  //  [39680,40192)  invQ[64], invK[64]
  __shared__ __align__(16) char smem[40192];
  float* qRaw = (float*)smem;
  float* kRaw = (float*)(smem + 12544);
  short8* KFh = (short8*)(smem + 25088);
  short8* KFl = (short8*)(smem + 31232);
  float* S_lds = (float*)smem;
  unsigned short* VTh = (unsigned short*)(smem + 16640);
  unsigned short* VTl = (unsigned short*)(smem + 23552);
  bf16* Pl = (bf16*)(smem + 30464);
  float* O_lds = (float*)smem;
  float* invQ = (float*)(smem + 39680);
  float* invK = (float*)(smem + 39936);

  const int bid = blockIdx.x;
  const int wid = ((bid & 7) << 8) | (bid >> 3);  // XCD swizzle (2048=8*256)
  const int wx = wid & 15, wy = (wid >> 4) & 15;
  const int head = wid >> 8;
  const int tid = threadIdx.x;
  const int lane = tid & 63, w = tid >> 6;
  const int lm = lane & 15, lq = lane >> 4;
  const int ybase = wy * 8, xbase = wx * 8;
  const size_t hb = (size_t)(head * CH) * HW;

  // phase 0: q,k windows -> raw LDS (float4 global loads)
#pragma unroll
  for (int i = 0; i < 6; i++) {
    const int s4 = tid + i * 256;  // [0,1536)
    const int t = s4 >= 768;
    const int r4 = s4 - t * 768;
    const int cc = r4 >> 4, nq = r4 & 15;
    const int n = nq * 4;
    const int y = ybase + (n >> 3), x = xbase + (n & 7);
    const float4 v4 = *(const float4*)(Bq + (size_t)(t * CDIM) * HW + hb +
                                       (size_t)cc * HW + y * 128 + x);
    float* dst = (t ? kRaw : qRaw) + n * 49 + cc;
    dst[0] = v4.x; dst[49] = v4.y; dst[98] = v4.z; dst[147] = v4.w;
  }
  __syncthreads();  // b1

  // V loads (float4) issued early; converted+written to VT post-b2.5
  float4 vv[3];
#pragma unroll
  for (int i = 0; i < 3; i++) {
    const int e4 = tid + i * 256;  // [0,768)
    const int cc = e4 >> 4, n = (e4 & 15) * 4;
    const int y = ybase + (n >> 3), x = xbase + (n & 7);
    vv[i] = *(const float4*)(Bq + (size_t)(2 * CDIM) * HW + hb +
                             (size_t)cc * HW + y * 128 + x);
  }

  // norms (threads 0..127); temperature folded into invQ
  if (tid < 128) {
    const int t = tid >> 6, n = tid & 63;
    const float* src = (t ? kRaw : qRaw) + n * 49;
    float ssum = 0.f;
#pragma unroll
    for (int cc = 0; cc < 48; cc++) { float v = src[cc]; ssum += v * v; }
    const float iv = 1.f / fmaxf(sqrtf(ssum), 1e-12f);
    if (t) invK[n] = iv; else invQ[n] = iv * temp[head];
  }

  // cooperative K -> split-bf16 frags (once per block, not per wave)
  conv_frag_k(tid, kRaw, KFh, KFl);
  if (tid < 128) conv_frag_k(256 + tid, kRaw, KFh, KFl);

  // Q A-frags (per-wave rows, not redundant): Q[w*16+lm][ks*32+lq*8+j]
  short8 qh[2], ql[2];
#pragma unroll
  for (int ks = 0; ks < 2; ks++) {
    const int ch0 = ks * 32 + lq * 8;
    const float* qp = qRaw + (w * 16 + lm) * 49 + ch0;
#pragma unroll
    for (int j = 0; j < 8; j++) {
      const float v = (ch0 < 48) ? qp[j] : 0.f;
      const unsigned short hbts = f2bf_bits(v);
      qh[ks][j] = (short)hbts;
      ql[ks][j] = (short)f2bf_bits(v - bfbits2f(hbts));
    }
  }
  __syncthreads();  // b2: KF + invs ready; raw regions dead

  // QK^T: 24 MFMAs (hi*hi + hi*lo + lo*hi per ks)
  f32x4 sacc[4] = {};
#pragma unroll
  for (int nt = 0; nt < 4; nt++) {
    const short8 kh0 = KFh[nt * 64 + lane];
    const short8 kl0 = KFl[nt * 64 + lane];
    sacc[nt] = __builtin_amdgcn_mfma_f32_16x16x32_bf16(qh[0], kh0, sacc[nt], 0, 0, 0);
    sacc[nt] = __builtin_amdgcn_mfma_f32_16x16x32_bf16(qh[0], kl0, sacc[nt], 0, 0, 0);
    sacc[nt] = __builtin_amdgcn_mfma_f32_16x16x32_bf16(ql[0], kh0, sacc[nt], 0, 0, 0);
    short8 kh1 = {0, 0, 0, 0, 0, 0, 0, 0}, kl1 = {0, 0, 0, 0, 0, 0, 0, 0};
    if (lane < 32) { kh1 = KFh[256 + nt * 32 + lane]; kl1 = KFl[256 + nt * 32 + lane]; }
    sacc[nt] = __builtin_amdgcn_mfma_f32_16x16x32_bf16(qh[1], kh1, sacc[nt], 0, 0, 0);
    sacc[nt] = __builtin_amdgcn_mfma_f32_16x16x32_bf16(qh[1], kl1, sacc[nt], 0, 0, 0);
    sacc[nt] = __builtin_amdgcn_mfma_f32_16x16x32_bf16(ql[1], kh1, sacc[nt], 0, 0, 0);
  }

  // scaled S -> LDS. D layout: row = w*16+lq*4+r, col = nt*16+lm.
  float iqv[4];
#pragma unroll
  for (int r = 0; r < 4; r++) iqv[r] = invQ[w * 16 + lq * 4 + r];
#pragma unroll
  for (int nt = 0; nt < 4; nt++) {
    const float ik = invK[nt * 16 + lm];
#pragma unroll
    for (int r = 0; r < 4; r++)
      S_lds[(w * 16 + lq * 4 + r) * 65 + nt * 16 + lm] = sacc[nt][r] * iqv[r] * ik;
  }
  __syncthreads();  // b2.5: all QK done; KF + raw regions dead

  // V regs -> split-bf16 directly into frag-layout VT[ch][72]
#pragma unroll
  for (int i = 0; i < 3; i++) {
    const int e4 = tid + i * 256;
    const int cc = e4 >> 4, n = (e4 & 15) * 4;
    const float v0 = vv[i].x, v1 = vv[i].y, v2 = vv[i].z, v3 = vv[i].w;
    const unsigned short h0 = f2bf_bits(v0), h1 = f2bf_bits(v1),
                         h2 = f2bf_bits(v2), h3 = f2bf_bits(v3);
    const ushort4 hh = {h0, h1, h2, h3};
    const ushort4 ll = {f2bf_bits(v0 - bfbits2f(h0)), f2bf_bits(v1 - bfbits2f(h1)),
                        f2bf_bits(v2 - bfbits2f(h2)), f2bf_bits(v3 - bfbits2f(h3))};
    *(ushort4*)(VTh + cc * 72 + n) = hh;
    *(ushort4*)(VTl + cc * 72 + n) = ll;
  }

  // softmax + top-k per row. Ascending bitonic sort (DPP for j=1,2,8),
  // then suffix-scan of exp over sorted values -> all 4 denominators.
  const float wts[4] = {a1[0], a2[0], a3[0], a4[0]};
  const int sidx[4] = {32, 22, 16, 13};  // 64-k for k in {32,42,48,51}
#pragma unroll 4
  for (int rr = 0; rr < 16; rr++) {
    const int row = w * 16 + rr;
    const float a = S_lds[row * 65 + lane];
    float s = a;
#pragma unroll
    for (int k2 = 2; k2 <= 64; k2 <<= 1) {
#pragma unroll
      for (int j = k2 >> 1; j > 0; j >>= 1) {
        float o;
        if (j == 1)      o = dppf<0xB1>(s);   // quad_perm xor1
        else if (j == 2) o = dppf<0x4E>(s);   // quad_perm xor2
        else if (j == 8) o = dppf<0x128>(s);  // row_ror:8 == xor8 in 16
        else             o = __shfl_xor(s, j);
        const bool up = ((lane & k2) == 0);
        const bool lower = ((lane & j) == 0);
        const float mn = fminf(s, o), mx = fmaxf(s, o);
        s = (lower == up) ? mn : mx;
      }
    }
    const float m = __shfl(s, 63);
    // inclusive suffix scan of exp(sorted - m): within-16 via DPP row_shl,
    // cross-row via 3 readlane row totals.
    float v = __expf(s - m);
    v += dppf<0x101>(v);  // row_shl:1
    v += dppf<0x102>(v);  // row_shl:2
    v += dppf<0x104>(v);  // row_shl:4
    v += dppf<0x108>(v);  // row_shl:8
    const float t1 = __shfl(v, 16), t2 = __shfl(v, 32), t3 = __shfl(v, 48);
    const float beyond =
        (lq == 0) ? (t1 + t2 + t3) : (lq == 1) ? (t2 + t3) : (lq == 2) ? t3 : 0.f;
    const float suf = v + beyond;  // suf[l] = sum_{j>=l} exp(s_j - m)
    const float e = __expf(a - m);
    float coef = 0.f;
#pragma unroll
    for (int kk = 0; kk < 4; kk++) {
      const float tk = __shfl(s, sidx[kk]);
      const float Sk = __shfl(suf, sidx[kk]);
      if (a >= tk) coef += wts[kk] * __builtin_amdgcn_rcpf(Sk);
    }
    Pl[row * 72 + lane] = __float2bfloat16(e * coef);
  }
  __syncthreads();  // b3: VT ready, all softmax S-reads done

  // P.V: A = P (bf16), B = V (split hi/lo). 12 MFMAs.
  short8 pa[2];
#pragma unroll
  for (int ks = 0; ks < 2; ks++)
    pa[ks] = *reinterpret_cast<const short8*>(&Pl[(w * 16 + lm) * 72 + ks * 32 + lq * 8]);
  f32x4 oacc[3] = {};
#pragma unroll
  for (int nt = 0; nt < 3; nt++) {
    const int chv = nt * 16 + lm;
#pragma unroll
    for (int ks = 0; ks < 2; ks++) {
      const short8 vh = *reinterpret_cast<const short8*>(VTh + chv * 72 + ks * 32 + lq * 8);
      const short8 vl = *reinterpret_cast<const short8*>(VTl + chv * 72 + ks * 32 + lq * 8);
      oacc[nt] = __builtin_amdgcn_mfma_f32_16x16x32_bf16(pa[ks], vh, oacc[nt], 0, 0, 0);
      oacc[nt] = __builtin_amdgcn_mfma_f32_16x16x32_bf16(pa[ks], vl, oacc[nt], 0, 0, 0);
    }
  }
  // O -> LDS transposed [ch][tok] (over dead S region)
#pragma unroll
  for (int nt = 0; nt < 3; nt++)
#pragma unroll
    for (int r = 0; r < 4; r++)
      O_lds[(nt * 16 + lm) * 65 + w * 16 + lq * 4 + r] = oacc[nt][r];
  __syncthreads();  // b4

  // pure store (cout_kernel adds afterwards), float4-coalesced
  const int y_out = wy * 8 + (wx >> 1);
  const int x0 = (wx & 1) * 64;
#pragma unroll
  for (int i = 0; i < 3; i++) {
    const int s4 = tid + i * 256;
    const int cc = s4 >> 4, n = (s4 & 15) * 4;
    const float* op = O_lds + cc * 65 + n;
    const float4 o4 = {op[0], op[1], op[2], op[3]};
    *(float4*)(Cbuf + ((size_t)(head * CH + cc) * 128 + y_out) * 128 + x0 + n) = o4;
  }
}

// ---------------- launch ----------------
extern "C" void kernel_launch(void* const* d_in, const int* in_sizes, int n_in,
                              void* d_out, int out_size, void* d_ws, size_t ws_size,
                              hipStream_t stream) {
  const float* x = (const float*)d_in[0];
  const float* w_qkv = (const float*)d_in[1];
  const float* w_dw = (const float*)d_in[2];
  const float* w_proj = (const float*)d_in[3];
  const float* temp = (const float*)d_in[4];
  const float* a1 = (const float*)d_in[5];
  const float* a2 = (const float*)d_in[6];
  const float* a3 = (const float*)d_in[7];
  const float* a4 = (const float*)d_in[8];
  float* out = (float*)d_out;

  // ws layout (bytes):
  //   [0,         9437184)  cattn_part f32 (128*8*2304)
  //   [9437184,   9510912)  W48 f32
  //   [9510912,   9513984)  inv f32 (768)
  //   [9513984,  10398720)  wqkv_h bf16 bits (1152x384)
  //   [10398720, 11283456)  wqkv_l
  //   [11283456, 11578368)  wproj_h (384x384)
  //   [11578368, 11873280)  wproj_l
  //   [11873280, 87370752)  Bq f32 (1152x16384) = 75.5 MB
  //     Xtg hi/lo in Bq v-third during qkv phase; Ctg hi/lo in q-third for proj.
  // Peak 87.4 MB (<= proven 89.4 MB).
  char* ws = (char*)d_ws;
  float* cattn_part = (float*)ws;
  float* W48 = (float*)(ws + 9437184);
  float* inv = (float*)(ws + 9510912);
  unsigned short* wqkv_h = (unsigned short*)(ws + 9513984);
  unsigned short* wqkv_l = (unsigned short*)(ws + 10398720);
  unsigned short* wproj_h = (unsigned short*)(ws + 11283456);
  unsigned short* wproj_l = (unsigned short*)(ws + 11578368);
  float* Bq = (float*)(ws + 11873280);
  short8* Xtgh = (short8*)(ws + 11873280 + (size_t)2 * CDIM * HW * 4);
  short8* Xtgl = (short8*)(ws + 11873280 + (size_t)2 * CDIM * HW * 4 + 12582912);
  short8* Ctgh = (short8*)(ws + 11873280);
  short8* Ctgl = (short8*)(ws + 11873280 + 12582912);

  decomp_w<<<(3 * CDIM * CDIM + 255) / 256, 256, 0, stream>>>(w_qkv, wqkv_h, wqkv_l,
                                                              3 * CDIM * CDIM);
  decomp_w<<<(CDIM * CDIM + 255) / 256, 256, 0, stream>>>(w_proj, wproj_h, wproj_l,
                                                          CDIM * CDIM);

  for (int b = 0; b < 2; b++) {
    const float* xb = x + (size_t)b * CDIM * HW;
    float* ob = out + (size_t)b * CDIM * HW;

    transpose_frag<<<3072, 256, 0, stream>>>(xb, Xtgh, Xtgl);
    for (int t = 0; t < 3; t++) {
      gemm_mfma<<<dim3(HW / 128, CDIM / 64), 256, 0, stream>>>(
          wqkv_h + (size_t)t * CDIM * CDIM, wqkv_l + (size_t)t * CDIM * CDIM,
          Xtgh, Xtgl, ob);
      dwconv3<<<(CDIM * HW / 4) / 256, 256, 0, stream>>>(
          ob, w_dw + (size_t)t * CDIM * 9, Bq + (size_t)t * CDIM * HW);
    }

    chan_norms<<<2 * CDIM, 256, 0, stream>>>(Bq, inv);
    cattn_partial<<<dim3(NCHUNK, NHEADS), 256, 0, stream>>>(Bq, cattn_part);
    chan_softmax<<<NHEADS * 48, 64, 0, stream>>>(cattn_part, inv, temp, a1, a2, a3, a4, W48);
    spatial_kernel<<<NHEADS * 256, 256, 0, stream>>>(Bq, temp, a1, a2, a3, a4, ob);
    cout_kernel<<<dim3(HW / 64, NHEADS), 256, 0, stream>>>(W48, Bq, ob);

    transpose_frag<<<3072, 256, 0, stream>>>(ob, Ctgh, Ctgl);
    gemm_mfma<<<dim3(HW / 128, CDIM / 64), 256, 0, stream>>>(wproj_h, wproj_l,
                                                             Ctgh, Ctgl, ob);
  }

  (void)in_sizes; (void)n_in; (void)out_size; (void)ws_size;
}

// Round 6
// 757.247 us; speedup vs baseline: 1.8302x; 1.0624x over previous
//
#include <hip/hip_runtime.h>
#include <hip/hip_bf16.h>

// TKMDAttention on MI355X — round 13: round-12 fusion with the cattn pixel-map
// bug fixed. cattn output is identity in pixel position, so its V operand must
// be read at the STORE pixels (y_out row, x0..x0+63), not the window-gather
// pixels. Vc[ch][n] = v[ch][y_out*128+x0+n] loaded coalesced; V2 built from Vc.
//  - cout fused into spatial (18 extra MFMAs/wave into same oacc as PV).
//  - chan_norms fused into cattn_partial (atomicAdd sumsq); transpose_frag
//    zeroes sumsq.
// Shapes: b=2, C=384, H=W=128, heads=8, ch=48, crop=8, N=64.
// windowstoimg: token n of window (wy,wx) -> y = wy*8+(wx>>1), x = (wx&1)*64+n.
// top-k rule (tie-exact): keep i for k iff a_i >= k-th largest (ref "a >= kth").

#define HW 16384
#define CDIM 384
#define NHEADS 8
#define CH 48
#define NCHUNK 128

typedef __hip_bfloat16 bf16;
typedef __attribute__((ext_vector_type(8))) short short8;
typedef __attribute__((ext_vector_type(4))) float f32x4;

static __device__ __forceinline__ unsigned short f2bf_bits(float v) {
  bf16 b = __float2bfloat16(v);
  return __builtin_bit_cast(unsigned short, b);
}
static __device__ __forceinline__ float bfbits2f(unsigned short u) {
  return __bfloat162float(__builtin_bit_cast(bf16, u));
}

// DPP move: returns x moved by CTRL (0-fill on invalid when bound_ctrl=true).
template <int CTRL>
static __device__ __forceinline__ float dppf(float x) {
  return __builtin_bit_cast(
      float, __builtin_amdgcn_update_dpp(0, __builtin_bit_cast(int, x), CTRL,
                                         0xF, 0xF, true));
}
// quad_perm(1,0,3,2)=0xB1 (xor1), quad_perm(2,3,0,1)=0x4E (xor2),
// row_ror:8=0x128 (xor8 within 16), row_shl:d=0x100+d (lane i <- i+d, 0-fill).

// ---- weight decompose: v = hi(bf16) + lo(bf16) ----
__global__ __launch_bounds__(256) void decomp_w(const float* __restrict__ src,
                                                unsigned short* __restrict__ h,
                                                unsigned short* __restrict__ l, int n) {
  int i = blockIdx.x * 256 + threadIdx.x;
  if (i >= n) return;
  float v = src[i];
  unsigned short hb = f2bf_bits(v);
  h[i] = hb;
  l[i] = f2bf_bits(v - bfbits2f(hb));
}

// ---- transpose src[384][16384] fp32 -> fragment-order bf16 hi/lo ----
// Also zeroes sumsq[768] (block 0) for the following cattn_partial.
__global__ __launch_bounds__(256) void transpose_frag(const float* __restrict__ src,
                                                      short8* __restrict__ dh,
                                                      short8* __restrict__ dl,
                                                      float* __restrict__ sumsq) {
  if (blockIdx.x == 0 && threadIdx.x < 192) {
    const float4 z = {0.f, 0.f, 0.f, 0.f};
    ((float4*)sumsq)[threadIdx.x] = z;
  }
  const int o = blockIdx.x * 256 + threadIdx.x;  // [0, 786432)
  const int ptile = o / 768;
  const int rem = o - ptile * 768;
  const int kc = rem >> 6, lane = rem & 63;
  const int p = ptile * 16 + (lane & 15);
  const int kb = kc * 32 + (lane >> 4) * 8;
  short8 hh, ll;
#pragma unroll
  for (int j = 0; j < 8; j++) {
    float v = src[(size_t)(kb + j) * HW + p];
    unsigned short hb = f2bf_bits(v);
    hh[j] = (short)hb;
    ll[j] = (short)f2bf_bits(v - bfbits2f(hb));
  }
  dh[o] = hh;
  dl[o] = ll;
}

// ---- split-bf16 MFMA GEMM: Out[oc][p] = sum_k W[oc][k] X[k][p], K=384 ----
__global__ __launch_bounds__(256, 4) void gemm_mfma(const unsigned short* __restrict__ Wh,
                                                    const unsigned short* __restrict__ Wl,
                                                    const short8* __restrict__ Xh,
                                                    const short8* __restrict__ Xl,
                                                    float* __restrict__ Out) {
  const int tid = threadIdx.x;
  const int wave = tid >> 6, lane = tid & 63;
  const int lm = lane & 15, lq = lane >> 4;
  const int g = blockIdx.y * 128 + blockIdx.x;  // [0,768)
  const int xcd = g & 7, i = g >> 3;            // bijective remap
  const int bx = xcd * 16 + (i & 15);
  const int by = i >> 4;
  const int p0 = bx * 128;
  const int oc0 = by * 64;
  const int pt0 = bx * 8 + wave * 2;
  f32x4 acc[4][2] = {};
#pragma unroll
  for (int kc = 0; kc < 12; kc++) {
    short8 ah[4], al[4], bh[2], bl[2];
#pragma unroll
    for (int mt = 0; mt < 4; mt++) {
      const size_t off = (size_t)(oc0 + mt * 16 + lm) * 384 + kc * 32 + lq * 8;
      ah[mt] = *reinterpret_cast<const short8*>(Wh + off);
      al[mt] = *reinterpret_cast<const short8*>(Wl + off);
    }
#pragma unroll
    for (int nt = 0; nt < 2; nt++) {
      const size_t idx = (size_t)((pt0 + nt) * 12 + kc) * 64 + lane;
      bh[nt] = Xh[idx];
      bl[nt] = Xl[idx];
    }
#pragma unroll
    for (int mt = 0; mt < 4; mt++)
#pragma unroll
      for (int nt = 0; nt < 2; nt++) {
        acc[mt][nt] = __builtin_amdgcn_mfma_f32_16x16x32_bf16(ah[mt], bh[nt], acc[mt][nt], 0, 0, 0);
        acc[mt][nt] = __builtin_amdgcn_mfma_f32_16x16x32_bf16(ah[mt], bl[nt], acc[mt][nt], 0, 0, 0);
        acc[mt][nt] = __builtin_amdgcn_mfma_f32_16x16x32_bf16(al[mt], bh[nt], acc[mt][nt], 0, 0, 0);
      }
  }
#pragma unroll
  for (int mt = 0; mt < 4; mt++)
#pragma unroll
    for (int nt = 0; nt < 2; nt++)
#pragma unroll
      for (int r = 0; r < 4; r++) {
        const int oc = oc0 + mt * 16 + lq * 4 + r;
        const int p = p0 + (wave * 2 + nt) * 16 + lm;
        Out[(size_t)oc * HW + p] = acc[mt][nt][r];
      }
}

// ---- depthwise 3x3 pad1, 384 channels; 4 pixels/thread, float4 loads ----
__global__ __launch_bounds__(256) void dwconv3(const float* __restrict__ A,
                                               const float* __restrict__ wdw,
                                               float* __restrict__ Bq) {
  const int e = blockIdx.x * 256 + threadIdx.x;  // [0, 384*128*32)
  const int x4 = e & 31;
  const int y = (e >> 5) & 127;
  const int ch = e >> 12;
  const int x0 = x4 << 2;
  float w[9];
#pragma unroll
  for (int t = 0; t < 9; t++) w[t] = wdw[ch * 9 + t];
  const float* Ap = A + (size_t)ch * HW;
  float4 acc = {0.f, 0.f, 0.f, 0.f};
#pragma unroll
  for (int ky = 0; ky < 3; ky++) {
    const int yy = y + ky - 1;
    if (yy < 0 || yy > 127) continue;
    const float* row = Ap + yy * 128;
    const float4 c = *(const float4*)(row + x0);
    const float l = (x4 == 0) ? 0.f : row[x0 - 1];
    const float r = (x4 == 31) ? 0.f : row[x0 + 4];
    const float w0 = w[ky * 3], w1 = w[ky * 3 + 1], w2 = w[ky * 3 + 2];
    acc.x += w0 * l + w1 * c.x + w2 * c.y;
    acc.y += w0 * c.x + w1 * c.y + w2 * c.z;
    acc.z += w0 * c.y + w1 * c.z + w2 * c.w;
    acc.w += w0 * c.z + w1 * c.w + w2 * r;
  }
  *(float4*)(Bq + (size_t)e * 4) = acc;
}

// ---- channel-attn partials + fused channel sumsq accumulation ----
__global__ __launch_bounds__(256, 3) void cattn_partial(const float* __restrict__ Bq,
                                                        float* __restrict__ part,
                                                        float* __restrict__ sumsq) {
  __shared__ __align__(16) float qs[48 * 132];
  __shared__ __align__(16) float ks2[48 * 132];
  const int tid = threadIdx.x;
  const int chunk = blockIdx.x, h = blockIdx.y;
  const int p0 = chunk * 128;
#pragma unroll
  for (int i = 0; i < 12; i++) {
    const int s4 = tid + i * 256;
    const int t = s4 >= 1536;
    const int r4 = s4 - t * 1536;
    const int cc = r4 >> 5;
    const int px = (r4 & 31) << 2;
    const float4 v4 = *(const float4*)(Bq + (size_t)(t * CDIM + h * CH + cc) * HW + p0 + px);
    *(float4*)((t ? ks2 : qs) + cc * 132 + px) = v4;
  }
  __syncthreads();
  // fused norms: threads 0..95 reduce one channel's 128 px, atomicAdd
  if (tid < 96) {
    const int t = tid >= 48;
    const int cc = t ? tid - 48 : tid;
    const float* src = (t ? ks2 : qs) + cc * 132;
    float s = 0.f;
#pragma unroll
    for (int p = 0; p < 128; p += 4) {
      const float4 v = *(const float4*)(src + p);
      s += v.x * v.x + v.y * v.y + v.z * v.z + v.w * v.w;
    }
    atomicAdd(&sumsq[t * CDIM + h * CH + cc], s);
  }
  const int tx = tid & 15, ty = tid >> 4;
  const float* qb = qs + (ty * 3) * 132;
  const float* kb = ks2 + (tx * 3) * 132;
  float acc[3][3] = {};
  for (int pl = 0; pl < 128; pl += 4) {
    float4 qv[3], kv[3];
#pragma unroll
    for (int ii = 0; ii < 3; ii++) qv[ii] = *(const float4*)(qb + ii * 132 + pl);
#pragma unroll
    for (int jj = 0; jj < 3; jj++) kv[jj] = *(const float4*)(kb + jj * 132 + pl);
#pragma unroll
    for (int ii = 0; ii < 3; ii++)
#pragma unroll
      for (int jj = 0; jj < 3; jj++)
        acc[ii][jj] += qv[ii].x * kv[jj].x + qv[ii].y * kv[jj].y +
                       qv[ii].z * kv[jj].z + qv[ii].w * kv[jj].w;
  }
  float* rp = part + (size_t)(h * NCHUNK + chunk) * 2304;
#pragma unroll
  for (int ii = 0; ii < 3; ii++)
#pragma unroll
    for (int jj = 0; jj < 3; jj++)
      rp[(ty * 3 + ii) * 48 + tx * 3 + jj] = acc[ii][jj];
}

// ---- channel masked-softmax combine (reduce + inv inline) -> W48 ----
__global__ __launch_bounds__(64) void chan_softmax(
    const float* __restrict__ part, const float* __restrict__ sumsq,
    const float* __restrict__ temp, const float* __restrict__ a1,
    const float* __restrict__ a2, const float* __restrict__ a3,
    const float* __restrict__ a4, float* __restrict__ W48) {
  const int blk = blockIdx.x;  // h*48 + i
  const int i = blk % 48;
  const int h = blk / 48;
  const int lane = threadIdx.x;
  const float t = temp[h];
  float a = -3.0e38f;
  if (lane < 48) {
    const float* pp = part + (size_t)h * NCHUNK * 2304 + i * 48 + lane;
    float r = 0.f;
#pragma unroll 8
    for (int c = 0; c < NCHUNK; c++) r += pp[(size_t)c * 2304];
    const float iq = 1.f / fmaxf(sqrtf(sumsq[h * CH + i]), 1e-12f);
    const float ik = 1.f / fmaxf(sqrtf(sumsq[CDIM + h * CH + lane]), 1e-12f);
    a = t * iq * ik * r;
  }
  float m = a;
  for (int o = 32; o; o >>= 1) m = fmaxf(m, __shfl_xor(m, o));
  float e = (lane < 48) ? expf(a - m) : 0.f;
  int gt = 0;
  for (int j = 0; j < 48; j++) {
    float vj = __shfl(a, j);
    gt += (vj > a) ? 1 : 0;
  }
  const int ksel[4] = {24, 32, 36, 38};
  const float wts[4] = {a1[0], a2[0], a3[0], a4[0]};
  float coef = 0.f;
#pragma unroll
  for (int kk = 0; kk < 4; kk++) {
    float sel = (gt < ksel[kk]) ? e : 0.f;
    for (int o = 32; o; o >>= 1) sel += __shfl_xor(sel, o);
    if (gt < ksel[kk]) coef += wts[kk] / sel;
  }
  if (lane < 48) W48[(size_t)blk * 48 + lane] = e * coef;
}

// ---- cooperative split-bf16 frag converters ----
static __device__ __forceinline__ void conv_frag_k(int f, const float* kRaw,
                                                   short8* KFh, short8* KFl) {
  int nt, ks, slot;
  if (f < 256) { nt = f >> 6; ks = 0; slot = f & 63; }
  else { const int g2 = f - 256; nt = g2 >> 5; ks = 1; slot = g2 & 31; }
  const int tok = nt * 16 + (slot & 15);
  const int ch0 = ks * 32 + (slot >> 4) * 8;
  const float* src = kRaw + tok * 49 + ch0;
  short8 hh, ll;
#pragma unroll
  for (int j = 0; j < 8; j++) {
    const float v = src[j];
    const unsigned short hb = f2bf_bits(v);
    hh[j] = (short)hb;
    ll[j] = (short)f2bf_bits(v - bfbits2f(hb));
  }
  KFh[f] = hh;
  KFl[f] = ll;
}
// W48 (48x48) -> B-frag order (n=ch_out, k=j). f in [0,288).
static __device__ __forceinline__ void conv_frag_w(int f, const float* __restrict__ wsrc,
                                                   short8* WFh, short8* WFl) {
  int nt, n, k0;
  if (f < 192) { nt = f >> 6; const int slot = f & 63; n = slot & 15; k0 = (slot >> 4) * 8; }
  else { const int g2 = f - 192; nt = g2 >> 5; const int slot = g2 & 31; n = slot & 15; k0 = 32 + (slot >> 4) * 8; }
  const float* src = wsrc + (nt * 16 + n) * 48 + k0;
  short8 hh, ll;
#pragma unroll
  for (int j = 0; j < 8; j++) {
    const float v = src[j];
    const unsigned short hb = f2bf_bits(v);
    hh[j] = (short)hb;
    ll[j] = (short)f2bf_bits(v - bfbits2f(hb));
  }
  WFh[f] = hh;
  WFl[f] = ll;
}

// ---- window attention + fused channel-attn output ----
// Block = 1 window, 4 waves. Wave w owns output rows [16w,16w+16).
__global__ __launch_bounds__(256, 3) void spatial_kernel(
    const float* __restrict__ Bq, const float* __restrict__ W48,
    const float* __restrict__ temp, const float* __restrict__ a1,
    const float* __restrict__ a2, const float* __restrict__ a3,
    const float* __restrict__ a4, float* __restrict__ Cbuf) {
  // LDS (49408 B), lifetime-disjoint by barriers:
  //  [0,12544)      qRaw[64][49] f32     (b1..b2)
  //  [12544,25088)  kRaw[64][49] f32     (b1..b2)
  //  [25088,37376)  KFh/KFl short8[384]  (pre-b2..b2.5)
  //  [0,16640)      S[64][65] f32        (post-b2..pre-b3)
  //  [16640,30464)  VTh/VTl ush[48][72]  (post-b2.5..PV MFMAs)
  //  [30464,39680)  P bf16[64][72]       (softmax..pa; over dead KF tail)
  //  [0,16384)      V2h/V2l ush[64][64]  (post-b3, XOR-swizzled j-blocks)
  //  [39680,48896)  WFh/WFl short8[288]  (pre-b1..end; W48 frags)
  //  [16640,29120)  O[48][65] f32        (post-b3.5, over dead VT)
  //  [48896,49408)  invQ[64], invK[64]
  __shared__ __align__(16) char smem[49408];
  float* qRaw = (float*)smem;
  float* kRaw = (float*)(smem + 12544);
  short8* KFh = (short8*)(smem + 25088);
  short8* KFl = (short8*)(smem + 31232);
  float* S_lds = (float*)smem;
  unsigned short* VTh = (unsigned short*)(smem + 16640);
  unsigned short* VTl = (unsigned short*)(smem + 23552);
  bf16* Pl = (bf16*)(smem + 30464);
  unsigned short* V2h = (unsigned short*)smem;
  unsigned short* V2l = (unsigned short*)(smem + 8192);
  short8* WFh = (short8*)(smem + 39680);
  short8* WFl = (short8*)(smem + 44288);
  float* O_lds = (float*)(smem + 16640);
  float* invQ = (float*)(smem + 48896);
  float* invK = (float*)(smem + 49152);

  const int bid = blockIdx.x;
  const int wid = ((bid & 7) << 8) | (bid >> 3);  // XCD swizzle (2048=8*256)
  const int wx = wid & 15, wy = (wid >> 4) & 15;
  const int head = wid >> 8;
  const int tid = threadIdx.x;
  const int lane = tid & 63, w = tid >> 6;
  const int lm = lane & 15, lq = lane >> 4;
  const int ybase = wy * 8, xbase = wx * 8;
  const int y_out = wy * 8 + (wx >> 1);      // windowstoimg store row
  const int x0 = (wx & 1) * 64;              // windowstoimg store col base
  const size_t hb = (size_t)(head * CH) * HW;

  // phase 0: q,k windows -> raw LDS (float4 global loads)
#pragma unroll
  for (int i = 0; i < 6; i++) {
    const int s4 = tid + i * 256;  // [0,1536)
    const int t = s4 >= 768;
    const int r4 = s4 - t * 768;
    const int cc = r4 >> 4, nq = r4 & 15;
    const int n = nq * 4;
    const int y = ybase + (n >> 3), x = xbase + (n & 7);
    const float4 v4 = *(const float4*)(Bq + (size_t)(t * CDIM) * HW + hb +
                                       (size_t)cc * HW + y * 128 + x);
    float* dst = (t ? kRaw : qRaw) + n * 49 + cc;
    dst[0] = v4.x; dst[49] = v4.y; dst[98] = v4.z; dst[147] = v4.w;
  }
  // W48 -> split-bf16 B-frags (region never aliased; ready long before use)
  conv_frag_w(tid, W48 + (size_t)head * 2304, WFh, WFl);
  if (tid < 32) conv_frag_w(256 + tid, W48 + (size_t)head * 2304, WFh, WFl);
  __syncthreads();  // b1

  // V loads (float4) issued early.
  // vv: window-gather pixels (PV operand). vc: windowstoimg STORE pixels
  // (cattn operand — cattn is identity in pixel position!).
  float4 vv[3], vc[3];
#pragma unroll
  for (int i = 0; i < 3; i++) {
    const int e4 = tid + i * 256;  // [0,768)
    const int cc = e4 >> 4, n = (e4 & 15) * 4;
    const int y = ybase + (n >> 3), x = xbase + (n & 7);
    vv[i] = *(const float4*)(Bq + (size_t)(2 * CDIM) * HW + hb +
                             (size_t)cc * HW + y * 128 + x);
    vc[i] = *(const float4*)(Bq + (size_t)(2 * CDIM) * HW + hb +
                             (size_t)cc * HW + y_out * 128 + x0 + n);
  }

  // norms (threads 0..127); temperature folded into invQ
  if (tid < 128) {
    const int t = tid >> 6, n = tid & 63;
    const float* src = (t ? kRaw : qRaw) + n * 49;
    float ssum = 0.f;
#pragma unroll
    for (int cc = 0; cc < 48; cc++) { float v = src[cc]; ssum += v * v; }
    const float iv = 1.f / fmaxf(sqrtf(ssum), 1e-12f);
    if (t) invK[n] = iv; else invQ[n] = iv * temp[head];
  }

  // cooperative K -> split-bf16 frags
  conv_frag_k(tid, kRaw, KFh, KFl);
  if (tid < 128) conv_frag_k(256 + tid, kRaw, KFh, KFl);

  // Q A-frags: Q[w*16+lm][ks*32+lq*8+j]
  short8 qh[2], ql[2];
#pragma unroll
  for (int ks = 0; ks < 2; ks++) {
    const int ch0 = ks * 32 + lq * 8;
    const float* qp = qRaw + (w * 16 + lm) * 49 + ch0;
#pragma unroll
    for (int j = 0; j < 8; j++) {
      const float v = (ch0 < 48) ? qp[j] : 0.f;
      const unsigned short hbts = f2bf_bits(v);
      qh[ks][j] = (short)hbts;
      ql[ks][j] = (short)f2bf_bits(v - bfbits2f(hbts));
    }
  }
  __syncthreads();  // b2: KF + invs ready; raw regions dead

  // QK^T: 24 MFMAs (hi*hi + hi*lo + lo*hi per ks)
  f32x4 sacc[4] = {};
#pragma unroll
  for (int nt = 0; nt < 4; nt++) {
    const short8 kh0 = KFh[nt * 64 + lane];
    const short8 kl0 = KFl[nt * 64 + lane];
    sacc[nt] = __builtin_amdgcn_mfma_f32_16x16x32_bf16(qh[0], kh0, sacc[nt], 0, 0, 0);
    sacc[nt] = __builtin_amdgcn_mfma_f32_16x16x32_bf16(qh[0], kl0, sacc[nt], 0, 0, 0);
    sacc[nt] = __builtin_amdgcn_mfma_f32_16x16x32_bf16(ql[0], kh0, sacc[nt], 0, 0, 0);
    short8 kh1 = {0, 0, 0, 0, 0, 0, 0, 0}, kl1 = {0, 0, 0, 0, 0, 0, 0, 0};
    if (lane < 32) { kh1 = KFh[256 + nt * 32 + lane]; kl1 = KFl[256 + nt * 32 + lane]; }
    sacc[nt] = __builtin_amdgcn_mfma_f32_16x16x32_bf16(qh[1], kh1, sacc[nt], 0, 0, 0);
    sacc[nt] = __builtin_amdgcn_mfma_f32_16x16x32_bf16(qh[1], kl1, sacc[nt], 0, 0, 0);
    sacc[nt] = __builtin_amdgcn_mfma_f32_16x16x32_bf16(ql[1], kh1, sacc[nt], 0, 0, 0);
  }

  // scaled S -> LDS. D layout: row = w*16+lq*4+r, col = nt*16+lm.
  float iqv[4];
#pragma unroll
  for (int r = 0; r < 4; r++) iqv[r] = invQ[w * 16 + lq * 4 + r];
#pragma unroll
  for (int nt = 0; nt < 4; nt++) {
    const float ik = invK[nt * 16 + lm];
#pragma unroll
    for (int r = 0; r < 4; r++)
      S_lds[(w * 16 + lq * 4 + r) * 65 + nt * 16 + lm] = sacc[nt][r] * iqv[r] * ik;
  }
  __syncthreads();  // b2.5: all QK done; KF + raw regions dead

  // V(gather) regs -> split-bf16 frag-layout VT[ch][72] (B-operand for PV)
#pragma unroll
  for (int i = 0; i < 3; i++) {
    const int e4 = tid + i * 256;
    const int cc = e4 >> 4, n = (e4 & 15) * 4;
    const float v0 = vv[i].x, v1 = vv[i].y, v2 = vv[i].z, v3 = vv[i].w;
    const unsigned short h0 = f2bf_bits(v0), h1 = f2bf_bits(v1),
                         h2 = f2bf_bits(v2), h3 = f2bf_bits(v3);
    const ushort4 hh = {h0, h1, h2, h3};
    const ushort4 ll = {f2bf_bits(v0 - bfbits2f(h0)), f2bf_bits(v1 - bfbits2f(h1)),
                        f2bf_bits(v2 - bfbits2f(h2)), f2bf_bits(v3 - bfbits2f(h3))};
    *(ushort4*)(VTh + cc * 72 + n) = hh;
    *(ushort4*)(VTl + cc * 72 + n) = ll;
  }

  // softmax + top-k per row (bitonic DPP sort + suffix scan)
  const float wts[4] = {a1[0], a2[0], a3[0], a4[0]};
  const int sidx[4] = {32, 22, 16, 13};  // 64-k for k in {32,42,48,51}
#pragma unroll 4
  for (int rr = 0; rr < 16; rr++) {
    const int row = w * 16 + rr;
    const float a = S_lds[row * 65 + lane];
    float s = a;
#pragma unroll
    for (int k2 = 2; k2 <= 64; k2 <<= 1) {
#pragma unroll
      for (int j = k2 >> 1; j > 0; j >>= 1) {
        float o;
        if (j == 1)      o = dppf<0xB1>(s);   // quad_perm xor1
        else if (j == 2) o = dppf<0x4E>(s);   // quad_perm xor2
        else if (j == 8) o = dppf<0x128>(s);  // row_ror:8 == xor8 in 16
        else             o = __shfl_xor(s, j);
        const bool up = ((lane & k2) == 0);
        const bool lower = ((lane & j) == 0);
        const float mn = fminf(s, o), mx = fmaxf(s, o);
        s = (lower == up) ? mn : mx;
      }
    }
    const float m = __shfl(s, 63);
    float v = __expf(s - m);
    v += dppf<0x101>(v);  // row_shl:1
    v += dppf<0x102>(v);  // row_shl:2
    v += dppf<0x104>(v);  // row_shl:4
    v += dppf<0x108>(v);  // row_shl:8
    const float t1 = __shfl(v, 16), t2 = __shfl(v, 32), t3 = __shfl(v, 48);
    const float beyond =
        (lq == 0) ? (t1 + t2 + t3) : (lq == 1) ? (t2 + t3) : (lq == 2) ? t3 : 0.f;
    const float suf = v + beyond;  // suf[l] = sum_{j>=l} exp(s_j - m)
    const float e = __expf(a - m);
    float coef = 0.f;
#pragma unroll
    for (int kk = 0; kk < 4; kk++) {
      const float tk = __shfl(s, sidx[kk]);
      const float Sk = __shfl(suf, sidx[kk]);
      if (a >= tk) coef += wts[kk] * __builtin_amdgcn_rcpf(Sk);
    }
    Pl[row * 72 + lane] = __float2bfloat16(e * coef);
  }
  __syncthreads();  // b3: S dead; VT ready

  // V(store-pixel) regs -> V2[n][j] split-bf16 (A-operand for cattn), swizzled
#pragma unroll
  for (int i = 0; i < 3; i++) {
    const int e4 = tid + i * 256;
    const int cc = e4 >> 4, n0 = (e4 & 15) * 4;
#pragma unroll
    for (int dt = 0; dt < 4; dt++) {
      const int tok = n0 + dt;
      const float v = (dt == 0) ? vc[i].x : (dt == 1) ? vc[i].y
                     : (dt == 2) ? vc[i].z : vc[i].w;
      const unsigned short hv = f2bf_bits(v);
      const int col = ((((cc >> 3) ^ (tok & 7)) << 3) | (cc & 7));
      V2h[tok * 64 + col] = hv;
      V2l[tok * 64 + col] = f2bf_bits(v - bfbits2f(hv));
    }
  }
  {  // zero pads: logical j-blocks 6,7 (j 48..63)
    const int buf = tid >> 7, r2 = tid & 127;
    const int tok = r2 >> 1, jbl = 6 + (r2 & 1);
    const int phys = (jbl ^ (tok & 7)) << 3;
    const short8 z = {0, 0, 0, 0, 0, 0, 0, 0};
    *(short8*)((buf ? V2l : V2h) + tok * 64 + phys) = z;
  }
  __syncthreads();  // b3.2: V2 ready

  // P (own-wave rows, no barrier needed for Pl)
  short8 pa[2];
#pragma unroll
  for (int ks = 0; ks < 2; ks++)
    pa[ks] = *reinterpret_cast<const short8*>(&Pl[(w * 16 + lm) * 72 + ks * 32 + lq * 8]);
  // Vc A-frags from V2 (swizzled): A[m=store-idx][k=j channel]
  const int tokA = w * 16 + lm;
  short8 a2h[2], a2l[2];
#pragma unroll
  for (int ks = 0; ks < 2; ks++) {
    const int phys = (((ks * 4 + lq) ^ (lm & 7)) << 3);
    a2h[ks] = *reinterpret_cast<const short8*>(V2h + tokA * 64 + phys);
    a2l[ks] = *reinterpret_cast<const short8*>(V2l + tokA * 64 + phys);
  }
  f32x4 oacc[3] = {};
#pragma unroll
  for (int nt = 0; nt < 3; nt++) {
    const int chv = nt * 16 + lm;
    // PV: 4 MFMAs
#pragma unroll
    for (int ks = 0; ks < 2; ks++) {
      const short8 vh = *reinterpret_cast<const short8*>(VTh + chv * 72 + ks * 32 + lq * 8);
      const short8 vl = *reinterpret_cast<const short8*>(VTl + chv * 72 + ks * 32 + lq * 8);
      oacc[nt] = __builtin_amdgcn_mfma_f32_16x16x32_bf16(pa[ks], vh, oacc[nt], 0, 0, 0);
      oacc[nt] = __builtin_amdgcn_mfma_f32_16x16x32_bf16(pa[ks], vl, oacc[nt], 0, 0, 0);
    }
    // cattn (W48 . Vc): 6 MFMAs (3-term split x 2 ks)
    {
      const short8 wh0 = WFh[nt * 64 + lane];
      const short8 wl0 = WFl[nt * 64 + lane];
      oacc[nt] = __builtin_amdgcn_mfma_f32_16x16x32_bf16(a2h[0], wh0, oacc[nt], 0, 0, 0);
      oacc[nt] = __builtin_amdgcn_mfma_f32_16x16x32_bf16(a2h[0], wl0, oacc[nt], 0, 0, 0);
      oacc[nt] = __builtin_amdgcn_mfma_f32_16x16x32_bf16(a2l[0], wh0, oacc[nt], 0, 0, 0);
      short8 wh1 = {0, 0, 0, 0, 0, 0, 0, 0}, wl1 = {0, 0, 0, 0, 0, 0, 0, 0};
      if (lane < 32) { wh1 = WFh[192 + nt * 32 + lane]; wl1 = WFl[192 + nt * 32 + lane]; }
      oacc[nt] = __builtin_amdgcn_mfma_f32_16x16x32_bf16(a2h[1], wh1, oacc[nt], 0, 0, 0);
      oacc[nt] = __builtin_amdgcn_mfma_f32_16x16x32_bf16(a2h[1], wl1, oacc[nt], 0, 0, 0);
      oacc[nt] = __builtin_amdgcn_mfma_f32_16x16x32_bf16(a2l[1], wh1, oacc[nt], 0, 0, 0);
    }
  }
  __syncthreads();  // b3.5: all VT/V2/WF reads done

  // O -> LDS transposed [ch][store-idx] (over dead VT region)
#pragma unroll
  for (int nt = 0; nt < 3; nt++)
#pragma unroll
    for (int r = 0; r < 4; r++)
      O_lds[(nt * 16 + lm) * 65 + w * 16 + lq * 4 + r] = oacc[nt][r];
  __syncthreads();  // b4

  // pure store, float4-coalesced (spatial + channel attn fused)
#pragma unroll
  for (int i = 0; i < 3; i++) {
    const int s4 = tid + i * 256;
    const int cc = s4 >> 4, n = (s4 & 15) * 4;
    const float* op = O_lds + cc * 65 + n;
    const float4 o4 = {op[0], op[1], op[2], op[3]};
    *(float4*)(Cbuf + ((size_t)(head * CH + cc) * 128 + y_out) * 128 + x0 + n) = o4;
  }
}

// ---------------- launch ----------------
extern "C" void kernel_launch(void* const* d_in, const int* in_sizes, int n_in,
                              void* d_out, int out_size, void* d_ws, size_t ws_size,
                              hipStream_t stream) {
  const float* x = (const float*)d_in[0];
  const float* w_qkv = (const float*)d_in[1];
  const float* w_dw = (const float*)d_in[2];
  const float* w_proj = (const float*)d_in[3];
  const float* temp = (const float*)d_in[4];
  const float* a1 = (const float*)d_in[5];
  const float* a2 = (const float*)d_in[6];
  const float* a3 = (const float*)d_in[7];
  const float* a4 = (const float*)d_in[8];
  float* out = (float*)d_out;

  // ws layout (bytes):
  //   [0,         9437184)  cattn_part f32 (128*8*2304)
  //   [9437184,   9510912)  W48 f32
  //   [9510912,   9513984)  sumsq f32 (768)
  //   [9513984,  10398720)  wqkv_h bf16 bits (1152x384)
  //   [10398720, 11283456)  wqkv_l
  //   [11283456, 11578368)  wproj_h (384x384)
  //   [11578368, 11873280)  wproj_l
  //   [11873280, 87370752)  Bq f32 (1152x16384) = 75.5 MB
  //     Xtg hi/lo in Bq v-third during qkv phase; Ctg hi/lo in q-third for proj.
  // Peak 87.4 MB (<= proven 89.4 MB).
  char* ws = (char*)d_ws;
  float* cattn_part = (float*)ws;
  float* W48 = (float*)(ws + 9437184);
  float* sumsq = (float*)(ws + 9510912);
  unsigned short* wqkv_h = (unsigned short*)(ws + 9513984);
  unsigned short* wqkv_l = (unsigned short*)(ws + 10398720);
  unsigned short* wproj_h = (unsigned short*)(ws + 11283456);
  unsigned short* wproj_l = (unsigned short*)(ws + 11578368);
  float* Bq = (float*)(ws + 11873280);
  short8* Xtgh = (short8*)(ws + 11873280 + (size_t)2 * CDIM * HW * 4);
  short8* Xtgl = (short8*)(ws + 11873280 + (size_t)2 * CDIM * HW * 4 + 12582912);
  short8* Ctgh = (short8*)(ws + 11873280);
  short8* Ctgl = (short8*)(ws + 11873280 + 12582912);

  decomp_w<<<(3 * CDIM * CDIM + 255) / 256, 256, 0, stream>>>(w_qkv, wqkv_h, wqkv_l,
                                                              3 * CDIM * CDIM);
  decomp_w<<<(CDIM * CDIM + 255) / 256, 256, 0, stream>>>(w_proj, wproj_h, wproj_l,
                                                          CDIM * CDIM);

  for (int b = 0; b < 2; b++) {
    const float* xb = x + (size_t)b * CDIM * HW;
    float* ob = out + (size_t)b * CDIM * HW;

    transpose_frag<<<3072, 256, 0, stream>>>(xb, Xtgh, Xtgl, sumsq);  // zeroes sumsq
    for (int t = 0; t < 3; t++) {
      gemm_mfma<<<dim3(HW / 128, CDIM / 64), 256, 0, stream>>>(
          wqkv_h + (size_t)t * CDIM * CDIM, wqkv_l + (size_t)t * CDIM * CDIM,
          Xtgh, Xtgl, ob);
      dwconv3<<<(CDIM * HW / 4) / 256, 256, 0, stream>>>(
          ob, w_dw + (size_t)t * CDIM * 9, Bq + (size_t)t * CDIM * HW);
    }

    cattn_partial<<<dim3(NCHUNK, NHEADS), 256, 0, stream>>>(Bq, cattn_part, sumsq);
    chan_softmax<<<NHEADS * 48, 64, 0, stream>>>(cattn_part, sumsq, temp, a1, a2, a3, a4, W48);
    spatial_kernel<<<NHEADS * 256, 256, 0, stream>>>(Bq, W48, temp, a1, a2, a3, a4, ob);

    transpose_frag<<<3072, 256, 0, stream>>>(ob, Ctgh, Ctgl, sumsq);
    gemm_mfma<<<dim3(HW / 128, CDIM / 64), 256, 0, stream>>>(wproj_h, wproj_l,
                                                             Ctgh, Ctgl, ob);
  }

  (void)in_sizes; (void)n_in; (void)out_size; (void)ws_size;
}

// Round 7
// 735.068 us; speedup vs baseline: 1.8854x; 1.0302x over previous
//
#include <hip/hip_runtime.h>
#include <hip/hip_bf16.h>

// TKMDAttention on MI355X — round 14: spatial occupancy + LDS-conflict fix.
//  - V2 LDS region removed: cattn A-frags (Vc at store pixels) loaded per-lane
//    directly from the L2-hot v-plane (16 predicated scalar loads, issued
//    early) — kills the scalar ds_write_u16 bank conflicts (2.8M cyc) and
//    16 KB of LDS.
//  - WF (W48 frags) relocated over the dead S region post-b3; W48 floats
//    prefetched to regs at kernel start; cooperative convert+store + barrier.
//  - LDS 49408 -> 40192 (4 blocks/CU restored), launch_bounds (256,4).
//  - decomp_w merged into one dispatch.
// Shapes: b=2, C=384, H=W=128, heads=8, ch=48, crop=8, N=64.
// windowstoimg: token n of window (wy,wx) -> y = wy*8+(wx>>1), x = (wx&1)*64+n.
// top-k rule (tie-exact): keep i for k iff a_i >= k-th largest (ref "a >= kth").

#define HW 16384
#define CDIM 384
#define NHEADS 8
#define CH 48
#define NCHUNK 128

typedef __hip_bfloat16 bf16;
typedef __attribute__((ext_vector_type(8))) short short8;
typedef __attribute__((ext_vector_type(4))) float f32x4;

static __device__ __forceinline__ unsigned short f2bf_bits(float v) {
  bf16 b = __float2bfloat16(v);
  return __builtin_bit_cast(unsigned short, b);
}
static __device__ __forceinline__ float bfbits2f(unsigned short u) {
  return __bfloat162float(__builtin_bit_cast(bf16, u));
}

// DPP move: returns x moved by CTRL (0-fill on invalid when bound_ctrl=true).
template <int CTRL>
static __device__ __forceinline__ float dppf(float x) {
  return __builtin_bit_cast(
      float, __builtin_amdgcn_update_dpp(0, __builtin_bit_cast(int, x), CTRL,
                                         0xF, 0xF, true));
}
// quad_perm(1,0,3,2)=0xB1 (xor1), quad_perm(2,3,0,1)=0x4E (xor2),
// row_ror:8=0x128 (xor8 within 16), row_shl:d=0x100+d (lane i <- i+d, 0-fill).

// ---- weight decompose (qkv + proj in one dispatch) ----
__global__ __launch_bounds__(256) void decomp_all(const float* __restrict__ wq,
                                                  const float* __restrict__ wp,
                                                  unsigned short* __restrict__ qh,
                                                  unsigned short* __restrict__ ql,
                                                  unsigned short* __restrict__ ph,
                                                  unsigned short* __restrict__ pl) {
  const int i = blockIdx.x * 256 + threadIdx.x;
  const int nq = 3 * CDIM * CDIM;
  if (i < nq) {
    const float v = wq[i];
    const unsigned short hb = f2bf_bits(v);
    qh[i] = hb;
    ql[i] = f2bf_bits(v - bfbits2f(hb));
  } else {
    const int k = i - nq;
    if (k < CDIM * CDIM) {
      const float v = wp[k];
      const unsigned short hb = f2bf_bits(v);
      ph[k] = hb;
      pl[k] = f2bf_bits(v - bfbits2f(hb));
    }
  }
}

// ---- transpose src[384][16384] fp32 -> fragment-order bf16 hi/lo ----
// Also zeroes sumsq[768] (block 0) for the following cattn_partial.
__global__ __launch_bounds__(256) void transpose_frag(const float* __restrict__ src,
                                                      short8* __restrict__ dh,
                                                      short8* __restrict__ dl,
                                                      float* __restrict__ sumsq) {
  if (blockIdx.x == 0 && threadIdx.x < 192) {
    const float4 z = {0.f, 0.f, 0.f, 0.f};
    ((float4*)sumsq)[threadIdx.x] = z;
  }
  const int o = blockIdx.x * 256 + threadIdx.x;  // [0, 786432)
  const int ptile = o / 768;
  const int rem = o - ptile * 768;
  const int kc = rem >> 6, lane = rem & 63;
  const int p = ptile * 16 + (lane & 15);
  const int kb = kc * 32 + (lane >> 4) * 8;
  short8 hh, ll;
#pragma unroll
  for (int j = 0; j < 8; j++) {
    float v = src[(size_t)(kb + j) * HW + p];
    unsigned short hb = f2bf_bits(v);
    hh[j] = (short)hb;
    ll[j] = (short)f2bf_bits(v - bfbits2f(hb));
  }
  dh[o] = hh;
  dl[o] = ll;
}

// ---- split-bf16 MFMA GEMM: Out[oc][p] = sum_k W[oc][k] X[k][p], K=384 ----
__global__ __launch_bounds__(256, 4) void gemm_mfma(const unsigned short* __restrict__ Wh,
                                                    const unsigned short* __restrict__ Wl,
                                                    const short8* __restrict__ Xh,
                                                    const short8* __restrict__ Xl,
                                                    float* __restrict__ Out) {
  const int tid = threadIdx.x;
  const int wave = tid >> 6, lane = tid & 63;
  const int lm = lane & 15, lq = lane >> 4;
  const int g = blockIdx.y * 128 + blockIdx.x;  // [0,768)
  const int xcd = g & 7, i = g >> 3;            // bijective remap
  const int bx = xcd * 16 + (i & 15);
  const int by = i >> 4;
  const int p0 = bx * 128;
  const int oc0 = by * 64;
  const int pt0 = bx * 8 + wave * 2;
  f32x4 acc[4][2] = {};
#pragma unroll
  for (int kc = 0; kc < 12; kc++) {
    short8 ah[4], al[4], bh[2], bl[2];
#pragma unroll
    for (int mt = 0; mt < 4; mt++) {
      const size_t off = (size_t)(oc0 + mt * 16 + lm) * 384 + kc * 32 + lq * 8;
      ah[mt] = *reinterpret_cast<const short8*>(Wh + off);
      al[mt] = *reinterpret_cast<const short8*>(Wl + off);
    }
#pragma unroll
    for (int nt = 0; nt < 2; nt++) {
      const size_t idx = (size_t)((pt0 + nt) * 12 + kc) * 64 + lane;
      bh[nt] = Xh[idx];
      bl[nt] = Xl[idx];
    }
#pragma unroll
    for (int mt = 0; mt < 4; mt++)
#pragma unroll
      for (int nt = 0; nt < 2; nt++) {
        acc[mt][nt] = __builtin_amdgcn_mfma_f32_16x16x32_bf16(ah[mt], bh[nt], acc[mt][nt], 0, 0, 0);
        acc[mt][nt] = __builtin_amdgcn_mfma_f32_16x16x32_bf16(ah[mt], bl[nt], acc[mt][nt], 0, 0, 0);
        acc[mt][nt] = __builtin_amdgcn_mfma_f32_16x16x32_bf16(al[mt], bh[nt], acc[mt][nt], 0, 0, 0);
      }
  }
#pragma unroll
  for (int mt = 0; mt < 4; mt++)
#pragma unroll
    for (int nt = 0; nt < 2; nt++)
#pragma unroll
      for (int r = 0; r < 4; r++) {
        const int oc = oc0 + mt * 16 + lq * 4 + r;
        const int p = p0 + (wave * 2 + nt) * 16 + lm;
        Out[(size_t)oc * HW + p] = acc[mt][nt][r];
      }
}

// ---- depthwise 3x3 pad1, 384 channels; 4 pixels/thread, float4 loads ----
__global__ __launch_bounds__(256) void dwconv3(const float* __restrict__ A,
                                               const float* __restrict__ wdw,
                                               float* __restrict__ Bq) {
  const int e = blockIdx.x * 256 + threadIdx.x;  // [0, 384*128*32)
  const int x4 = e & 31;
  const int y = (e >> 5) & 127;
  const int ch = e >> 12;
  const int x0 = x4 << 2;
  float w[9];
#pragma unroll
  for (int t = 0; t < 9; t++) w[t] = wdw[ch * 9 + t];
  const float* Ap = A + (size_t)ch * HW;
  float4 acc = {0.f, 0.f, 0.f, 0.f};
#pragma unroll
  for (int ky = 0; ky < 3; ky++) {
    const int yy = y + ky - 1;
    if (yy < 0 || yy > 127) continue;
    const float* row = Ap + yy * 128;
    const float4 c = *(const float4*)(row + x0);
    const float l = (x4 == 0) ? 0.f : row[x0 - 1];
    const float r = (x4 == 31) ? 0.f : row[x0 + 4];
    const float w0 = w[ky * 3], w1 = w[ky * 3 + 1], w2 = w[ky * 3 + 2];
    acc.x += w0 * l + w1 * c.x + w2 * c.y;
    acc.y += w0 * c.x + w1 * c.y + w2 * c.z;
    acc.z += w0 * c.y + w1 * c.z + w2 * c.w;
    acc.w += w0 * c.z + w1 * c.w + w2 * r;
  }
  *(float4*)(Bq + (size_t)e * 4) = acc;
}

// ---- channel-attn partials + fused channel sumsq accumulation ----
__global__ __launch_bounds__(256, 3) void cattn_partial(const float* __restrict__ Bq,
                                                        float* __restrict__ part,
                                                        float* __restrict__ sumsq) {
  __shared__ __align__(16) float qs[48 * 132];
  __shared__ __align__(16) float ks2[48 * 132];
  const int tid = threadIdx.x;
  const int chunk = blockIdx.x, h = blockIdx.y;
  const int p0 = chunk * 128;
#pragma unroll
  for (int i = 0; i < 12; i++) {
    const int s4 = tid + i * 256;
    const int t = s4 >= 1536;
    const int r4 = s4 - t * 1536;
    const int cc = r4 >> 5;
    const int px = (r4 & 31) << 2;
    const float4 v4 = *(const float4*)(Bq + (size_t)(t * CDIM + h * CH + cc) * HW + p0 + px);
    *(float4*)((t ? ks2 : qs) + cc * 132 + px) = v4;
  }
  __syncthreads();
  // fused norms: threads 0..95 reduce one channel's 128 px, atomicAdd
  if (tid < 96) {
    const int t = tid >= 48;
    const int cc = t ? tid - 48 : tid;
    const float* src = (t ? ks2 : qs) + cc * 132;
    float s = 0.f;
#pragma unroll
    for (int p = 0; p < 128; p += 4) {
      const float4 v = *(const float4*)(src + p);
      s += v.x * v.x + v.y * v.y + v.z * v.z + v.w * v.w;
    }
    atomicAdd(&sumsq[t * CDIM + h * CH + cc], s);
  }
  const int tx = tid & 15, ty = tid >> 4;
  const float* qb = qs + (ty * 3) * 132;
  const float* kb = ks2 + (tx * 3) * 132;
  float acc[3][3] = {};
  for (int pl = 0; pl < 128; pl += 4) {
    float4 qv[3], kv[3];
#pragma unroll
    for (int ii = 0; ii < 3; ii++) qv[ii] = *(const float4*)(qb + ii * 132 + pl);
#pragma unroll
    for (int jj = 0; jj < 3; jj++) kv[jj] = *(const float4*)(kb + jj * 132 + pl);
#pragma unroll
    for (int ii = 0; ii < 3; ii++)
#pragma unroll
      for (int jj = 0; jj < 3; jj++)
        acc[ii][jj] += qv[ii].x * kv[jj].x + qv[ii].y * kv[jj].y +
                       qv[ii].z * kv[jj].z + qv[ii].w * kv[jj].w;
  }
  float* rp = part + (size_t)(h * NCHUNK + chunk) * 2304;
#pragma unroll
  for (int ii = 0; ii < 3; ii++)
#pragma unroll
    for (int jj = 0; jj < 3; jj++)
      rp[(ty * 3 + ii) * 48 + tx * 3 + jj] = acc[ii][jj];
}

// ---- channel masked-softmax combine (reduce + inv inline) -> W48 ----
__global__ __launch_bounds__(64) void chan_softmax(
    const float* __restrict__ part, const float* __restrict__ sumsq,
    const float* __restrict__ temp, const float* __restrict__ a1,
    const float* __restrict__ a2, const float* __restrict__ a3,
    const float* __restrict__ a4, float* __restrict__ W48) {
  const int blk = blockIdx.x;  // h*48 + i
  const int i = blk % 48;
  const int h = blk / 48;
  const int lane = threadIdx.x;
  const float t = temp[h];
  float a = -3.0e38f;
  if (lane < 48) {
    const float* pp = part + (size_t)h * NCHUNK * 2304 + i * 48 + lane;
    float r = 0.f;
#pragma unroll 8
    for (int c = 0; c < NCHUNK; c++) r += pp[(size_t)c * 2304];
    const float iq = 1.f / fmaxf(sqrtf(sumsq[h * CH + i]), 1e-12f);
    const float ik = 1.f / fmaxf(sqrtf(sumsq[CDIM + h * CH + lane]), 1e-12f);
    a = t * iq * ik * r;
  }
  float m = a;
  for (int o = 32; o; o >>= 1) m = fmaxf(m, __shfl_xor(m, o));
  float e = (lane < 48) ? expf(a - m) : 0.f;
  int gt = 0;
  for (int j = 0; j < 48; j++) {
    float vj = __shfl(a, j);
    gt += (vj > a) ? 1 : 0;
  }
  const int ksel[4] = {24, 32, 36, 38};
  const float wts[4] = {a1[0], a2[0], a3[0], a4[0]};
  float coef = 0.f;
#pragma unroll
  for (int kk = 0; kk < 4; kk++) {
    float sel = (gt < ksel[kk]) ? e : 0.f;
    for (int o = 32; o; o >>= 1) sel += __shfl_xor(sel, o);
    if (gt < ksel[kk]) coef += wts[kk] / sel;
  }
  if (lane < 48) W48[(size_t)blk * 48 + lane] = e * coef;
}

// ---- cooperative split-bf16 frag converter (K) ----
static __device__ __forceinline__ void conv_frag_k(int f, const float* kRaw,
                                                   short8* KFh, short8* KFl) {
  int nt, ks, slot;
  if (f < 256) { nt = f >> 6; ks = 0; slot = f & 63; }
  else { const int g2 = f - 256; nt = g2 >> 5; ks = 1; slot = g2 & 31; }
  const int tok = nt * 16 + (slot & 15);
  const int ch0 = ks * 32 + (slot >> 4) * 8;
  const float* src = kRaw + tok * 49 + ch0;
  short8 hh, ll;
#pragma unroll
  for (int j = 0; j < 8; j++) {
    const float v = src[j];
    const unsigned short hb = f2bf_bits(v);
    hh[j] = (short)hb;
    ll[j] = (short)f2bf_bits(v - bfbits2f(hb));
  }
  KFh[f] = hh;
  KFl[f] = ll;
}
// W48 frag f -> float offset of its 8-element run in the per-head W48.
static __device__ __forceinline__ int wfrag_off(int f) {
  int nt, n, k0;
  if (f < 192) { nt = f >> 6; const int slot = f & 63; n = slot & 15; k0 = (slot >> 4) * 8; }
  else { const int g2 = f - 192; nt = g2 >> 5; const int slot = g2 & 31; n = slot & 15; k0 = 32 + (slot >> 4) * 8; }
  return (nt * 16 + n) * 48 + k0;
}

// ---- window attention + fused channel-attn output ----
// Block = 1 window, 4 waves. Wave w owns output rows [16w,16w+16).
__global__ __launch_bounds__(256, 4) void spatial_kernel(
    const float* __restrict__ Bq, const float* __restrict__ W48,
    const float* __restrict__ temp, const float* __restrict__ a1,
    const float* __restrict__ a2_, const float* __restrict__ a3,
    const float* __restrict__ a4, float* __restrict__ Cbuf) {
  // LDS (40192 B), lifetime-disjoint by barriers:
  //  [0,12544)      qRaw[64][49] f32     (b1..b2)
  //  [12544,25088)  kRaw[64][49] f32     (b1..b2)
  //  [25088,37376)  KFh/KFl short8[384]  (pre-b2..b2.5)
  //  [0,16640)      S[64][65] f32        (post-b2..b3; reads wave-local)
  //  [16640,30464)  VTh/VTl ush[48][72]  (post-b2.5..b3.5)
  //  [30464,39680)  P bf16[64][72]       (softmax..pa)
  //  [0,9216)       WFh/WFl short8[288]  (post-b3, over dead S)
  //  [16640,29120)  O[48][65] f32        (post-b3.5, over dead VT)
  //  [39680,40192)  invQ[64], invK[64]
  __shared__ __align__(16) char smem[40192];
  float* qRaw = (float*)smem;
  float* kRaw = (float*)(smem + 12544);
  short8* KFh = (short8*)(smem + 25088);
  short8* KFl = (short8*)(smem + 31232);
  float* S_lds = (float*)smem;
  unsigned short* VTh = (unsigned short*)(smem + 16640);
  unsigned short* VTl = (unsigned short*)(smem + 23552);
  bf16* Pl = (bf16*)(smem + 30464);
  short8* WFh = (short8*)smem;
  short8* WFl = (short8*)(smem + 4608);
  float* O_lds = (float*)(smem + 16640);
  float* invQ = (float*)(smem + 39680);
  float* invK = (float*)(smem + 39936);

  const int bid = blockIdx.x;
  const int wid = ((bid & 7) << 8) | (bid >> 3);  // XCD swizzle (2048=8*256)
  const int wx = wid & 15, wy = (wid >> 4) & 15;
  const int head = wid >> 8;
  const int tid = threadIdx.x;
  const int lane = tid & 63, w = tid >> 6;
  const int lm = lane & 15, lq = lane >> 4;
  const int ybase = wy * 8, xbase = wx * 8;
  const int y_out = wy * 8 + (wx >> 1);      // windowstoimg store row
  const int x0 = (wx & 1) * 64;              // windowstoimg store col base
  const size_t hb = (size_t)(head * CH) * HW;
  const float* wsrc = W48 + (size_t)head * 2304;

  // phase 0: q,k windows -> raw LDS (float4 global loads)
#pragma unroll
  for (int i = 0; i < 6; i++) {
    const int s4 = tid + i * 256;  // [0,1536)
    const int t = s4 >= 768;
    const int r4 = s4 - t * 768;
    const int cc = r4 >> 4, nq = r4 & 15;
    const int n = nq * 4;
    const int y = ybase + (n >> 3), x = xbase + (n & 7);
    const float4 v4 = *(const float4*)(Bq + (size_t)(t * CDIM) * HW + hb +
                                       (size_t)cc * HW + y * 128 + x);
    float* dst = (t ? kRaw : qRaw) + n * 49 + cc;
    dst[0] = v4.x; dst[49] = v4.y; dst[98] = v4.z; dst[147] = v4.w;
  }
  // W48 float prefetch (frags tid and 256+tid for tid<32); converted post-b3.
  float wpre0[8], wpre1[8];
  {
    const int off = wfrag_off(tid);
    const float4 a = *(const float4*)(wsrc + off);
    const float4 b = *(const float4*)(wsrc + off + 4);
    wpre0[0] = a.x; wpre0[1] = a.y; wpre0[2] = a.z; wpre0[3] = a.w;
    wpre0[4] = b.x; wpre0[5] = b.y; wpre0[6] = b.z; wpre0[7] = b.w;
  }
  if (tid < 32) {
    const int off = wfrag_off(256 + tid);
    const float4 a = *(const float4*)(wsrc + off);
    const float4 b = *(const float4*)(wsrc + off + 4);
    wpre1[0] = a.x; wpre1[1] = a.y; wpre1[2] = a.z; wpre1[3] = a.w;
    wpre1[4] = b.x; wpre1[5] = b.y; wpre1[6] = b.z; wpre1[7] = b.w;
  }
  __syncthreads();  // b1

  // V(gather) loads (float4) for PV; Vc per-lane strided loads (cattn A-frag
  // source: 16 channel values at this lane's STORE pixel). All issued early.
  float4 vv[3];
#pragma unroll
  for (int i = 0; i < 3; i++) {
    const int e4 = tid + i * 256;  // [0,768)
    const int cc = e4 >> 4, n = (e4 & 15) * 4;
    const int y = ybase + (n >> 3), x = xbase + (n & 7);
    vv[i] = *(const float4*)(Bq + (size_t)(2 * CDIM) * HW + hb +
                             (size_t)cc * HW + y * 128 + x);
  }
  float af[16];
  {
    const int px = y_out * 128 + x0 + (w * 16 + lm);
    const float* vpl = Bq + (size_t)(2 * CDIM) * HW + hb + px;
#pragma unroll
    for (int ks = 0; ks < 2; ks++)
#pragma unroll
      for (int j = 0; j < 8; j++) {
        const int ch = ks * 32 + lq * 8 + j;
        af[ks * 8 + j] = (ch < 48) ? vpl[(size_t)ch * HW] : 0.f;
      }
  }

  // norms (threads 0..127); temperature folded into invQ
  if (tid < 128) {
    const int t = tid >> 6, n = tid & 63;
    const float* src = (t ? kRaw : qRaw) + n * 49;
    float ssum = 0.f;
#pragma unroll
    for (int cc = 0; cc < 48; cc++) { float v = src[cc]; ssum += v * v; }
    const float iv = 1.f / fmaxf(sqrtf(ssum), 1e-12f);
    if (t) invK[n] = iv; else invQ[n] = iv * temp[head];
  }

  // cooperative K -> split-bf16 frags
  conv_frag_k(tid, kRaw, KFh, KFl);
  if (tid < 128) conv_frag_k(256 + tid, kRaw, KFh, KFl);

  // Q A-frags: Q[w*16+lm][ks*32+lq*8+j]
  short8 qh[2], ql[2];
#pragma unroll
  for (int ks = 0; ks < 2; ks++) {
    const int ch0 = ks * 32 + lq * 8;
    const float* qp = qRaw + (w * 16 + lm) * 49 + ch0;
#pragma unroll
    for (int j = 0; j < 8; j++) {
      const float v = (ch0 < 48) ? qp[j] : 0.f;
      const unsigned short hbts = f2bf_bits(v);
      qh[ks][j] = (short)hbts;
      ql[ks][j] = (short)f2bf_bits(v - bfbits2f(hbts));
    }
  }
  __syncthreads();  // b2: KF + invs ready; raw regions dead

  // QK^T: 24 MFMAs (hi*hi + hi*lo + lo*hi per ks)
  f32x4 sacc[4] = {};
#pragma unroll
  for (int nt = 0; nt < 4; nt++) {
    const short8 kh0 = KFh[nt * 64 + lane];
    const short8 kl0 = KFl[nt * 64 + lane];
    sacc[nt] = __builtin_amdgcn_mfma_f32_16x16x32_bf16(qh[0], kh0, sacc[nt], 0, 0, 0);
    sacc[nt] = __builtin_amdgcn_mfma_f32_16x16x32_bf16(qh[0], kl0, sacc[nt], 0, 0, 0);
    sacc[nt] = __builtin_amdgcn_mfma_f32_16x16x32_bf16(ql[0], kh0, sacc[nt], 0, 0, 0);
    short8 kh1 = {0, 0, 0, 0, 0, 0, 0, 0}, kl1 = {0, 0, 0, 0, 0, 0, 0, 0};
    if (lane < 32) { kh1 = KFh[256 + nt * 32 + lane]; kl1 = KFl[256 + nt * 32 + lane]; }
    sacc[nt] = __builtin_amdgcn_mfma_f32_16x16x32_bf16(qh[1], kh1, sacc[nt], 0, 0, 0);
    sacc[nt] = __builtin_amdgcn_mfma_f32_16x16x32_bf16(qh[1], kl1, sacc[nt], 0, 0, 0);
    sacc[nt] = __builtin_amdgcn_mfma_f32_16x16x32_bf16(ql[1], kh1, sacc[nt], 0, 0, 0);
  }

  // scaled S -> LDS. D layout: row = w*16+lq*4+r, col = nt*16+lm.
  float iqv[4];
#pragma unroll
  for (int r = 0; r < 4; r++) iqv[r] = invQ[w * 16 + lq * 4 + r];
#pragma unroll
  for (int nt = 0; nt < 4; nt++) {
    const float ik = invK[nt * 16 + lm];
#pragma unroll
    for (int r = 0; r < 4; r++)
      S_lds[(w * 16 + lq * 4 + r) * 65 + nt * 16 + lm] = sacc[nt][r] * iqv[r] * ik;
  }
  __syncthreads();  // b2.5: all QK done; KF + raw regions dead

  // V(gather) regs -> split-bf16 frag-layout VT[ch][72] (B-operand for PV)
#pragma unroll
  for (int i = 0; i < 3; i++) {
    const int e4 = tid + i * 256;
    const int cc = e4 >> 4, n = (e4 & 15) * 4;
    const float v0 = vv[i].x, v1 = vv[i].y, v2 = vv[i].z, v3 = vv[i].w;
    const unsigned short h0 = f2bf_bits(v0), h1 = f2bf_bits(v1),
                         h2 = f2bf_bits(v2), h3 = f2bf_bits(v3);
    const ushort4 hh = {h0, h1, h2, h3};
    const ushort4 ll = {f2bf_bits(v0 - bfbits2f(h0)), f2bf_bits(v1 - bfbits2f(h1)),
                        f2bf_bits(v2 - bfbits2f(h2)), f2bf_bits(v3 - bfbits2f(h3))};
    *(ushort4*)(VTh + cc * 72 + n) = hh;
    *(ushort4*)(VTl + cc * 72 + n) = ll;
  }

  // softmax + top-k per row (bitonic DPP sort + suffix scan)
  const float wts[4] = {a1[0], a2_[0], a3[0], a4[0]};
  const int sidx[4] = {32, 22, 16, 13};  // 64-k for k in {32,42,48,51}
#pragma unroll 4
  for (int rr = 0; rr < 16; rr++) {
    const int row = w * 16 + rr;
    const float a = S_lds[row * 65 + lane];
    float s = a;
#pragma unroll
    for (int k2 = 2; k2 <= 64; k2 <<= 1) {
#pragma unroll
      for (int j = k2 >> 1; j > 0; j >>= 1) {
        float o;
        if (j == 1)      o = dppf<0xB1>(s);   // quad_perm xor1
        else if (j == 2) o = dppf<0x4E>(s);   // quad_perm xor2
        else if (j == 8) o = dppf<0x128>(s);  // row_ror:8 == xor8 in 16
        else             o = __shfl_xor(s, j);
        const bool up = ((lane & k2) == 0);
        const bool lower = ((lane & j) == 0);
        const float mn = fminf(s, o), mx = fmaxf(s, o);
        s = (lower == up) ? mn : mx;
      }
    }
    const float m = __shfl(s, 63);
    float v = __expf(s - m);
    v += dppf<0x101>(v);  // row_shl:1
    v += dppf<0x102>(v);  // row_shl:2
    v += dppf<0x104>(v);  // row_shl:4
    v += dppf<0x108>(v);  // row_shl:8
    const float t1 = __shfl(v, 16), t2 = __shfl(v, 32), t3 = __shfl(v, 48);
    const float beyond =
        (lq == 0) ? (t1 + t2 + t3) : (lq == 1) ? (t2 + t3) : (lq == 2) ? t3 : 0.f;
    const float suf = v + beyond;  // suf[l] = sum_{j>=l} exp(s_j - m)
    const float e = __expf(a - m);
    float coef = 0.f;
#pragma unroll
    for (int kk = 0; kk < 4; kk++) {
      const float tk = __shfl(s, sidx[kk]);
      const float Sk = __shfl(suf, sidx[kk]);
      if (a >= tk) coef += wts[kk] * __builtin_amdgcn_rcpf(Sk);
    }
    Pl[row * 72 + lane] = __float2bfloat16(e * coef);
  }
  __syncthreads();  // b3: all softmax S-reads done (S dead); VT ready

  // WF: convert prefetched W48 floats -> split-bf16 frags over dead S region
  {
    short8 hh, ll;
#pragma unroll
    for (int j = 0; j < 8; j++) {
      const float v = wpre0[j];
      const unsigned short hbw = f2bf_bits(v);
      hh[j] = (short)hbw;
      ll[j] = (short)f2bf_bits(v - bfbits2f(hbw));
    }
    WFh[tid] = hh;
    WFl[tid] = ll;
  }
  if (tid < 32) {
    short8 hh, ll;
#pragma unroll
    for (int j = 0; j < 8; j++) {
      const float v = wpre1[j];
      const unsigned short hbw = f2bf_bits(v);
      hh[j] = (short)hbw;
      ll[j] = (short)f2bf_bits(v - bfbits2f(hbw));
    }
    WFh[256 + tid] = hh;
    WFl[256 + tid] = ll;
  }
  // P frags (own-wave rows) and Vc A-frags from the early strided loads
  short8 pa[2];
#pragma unroll
  for (int ks = 0; ks < 2; ks++)
    pa[ks] = *reinterpret_cast<const short8*>(&Pl[(w * 16 + lm) * 72 + ks * 32 + lq * 8]);
  short8 a2h[2], a2l[2];
#pragma unroll
  for (int ks = 0; ks < 2; ks++)
#pragma unroll
    for (int j = 0; j < 8; j++) {
      const float v = af[ks * 8 + j];
      const unsigned short hv = f2bf_bits(v);
      a2h[ks][j] = (short)hv;
      a2l[ks][j] = (short)f2bf_bits(v - bfbits2f(hv));
    }
  __syncthreads();  // b3.2: WF ready

  f32x4 oacc[3] = {};
#pragma unroll
  for (int nt = 0; nt < 3; nt++) {
    const int chv = nt * 16 + lm;
    // PV: 4 MFMAs
#pragma unroll
    for (int ks = 0; ks < 2; ks++) {
      const short8 vh = *reinterpret_cast<const short8*>(VTh + chv * 72 + ks * 32 + lq * 8);
      const short8 vl = *reinterpret_cast<const short8*>(VTl + chv * 72 + ks * 32 + lq * 8);
      oacc[nt] = __builtin_amdgcn_mfma_f32_16x16x32_bf16(pa[ks], vh, oacc[nt], 0, 0, 0);
      oacc[nt] = __builtin_amdgcn_mfma_f32_16x16x32_bf16(pa[ks], vl, oacc[nt], 0, 0, 0);
    }
    // cattn (W48 . Vc): 6 MFMAs (3-term split x 2 ks)
    {
      const short8 wh0 = WFh[nt * 64 + lane];
      const short8 wl0 = WFl[nt * 64 + lane];
      oacc[nt] = __builtin_amdgcn_mfma_f32_16x16x32_bf16(a2h[0], wh0, oacc[nt], 0, 0, 0);
      oacc[nt] = __builtin_amdgcn_mfma_f32_16x16x32_bf16(a2h[0], wl0, oacc[nt], 0, 0, 0);
      oacc[nt] = __builtin_amdgcn_mfma_f32_16x16x32_bf16(a2l[0], wh0, oacc[nt], 0, 0, 0);
      short8 wh1 = {0, 0, 0, 0, 0, 0, 0, 0}, wl1 = {0, 0, 0, 0, 0, 0, 0, 0};
      if (lane < 32) { wh1 = WFh[192 + nt * 32 + lane]; wl1 = WFl[192 + nt * 32 + lane]; }
      oacc[nt] = __builtin_amdgcn_mfma_f32_16x16x32_bf16(a2h[1], wh1, oacc[nt], 0, 0, 0);
      oacc[nt] = __builtin_amdgcn_mfma_f32_16x16x32_bf16(a2h[1], wl1, oacc[nt], 0, 0, 0);
      oacc[nt] = __builtin_amdgcn_mfma_f32_16x16x32_bf16(a2l[1], wh1, oacc[nt], 0, 0, 0);
    }
  }
  __syncthreads();  // b3.5: all VT/WF reads done

  // O -> LDS transposed [ch][store-idx] (over dead VT region)
#pragma unroll
  for (int nt = 0; nt < 3; nt++)
#pragma unroll
    for (int r = 0; r < 4; r++)
      O_lds[(nt * 16 + lm) * 65 + w * 16 + lq * 4 + r] = oacc[nt][r];
  __syncthreads();  // b4

  // pure store, float4-coalesced (spatial + channel attn fused)
#pragma unroll
  for (int i = 0; i < 3; i++) {
    const int s4 = tid + i * 256;
    const int cc = s4 >> 4, n = (s4 & 15) * 4;
    const float* op = O_lds + cc * 65 + n;
    const float4 o4 = {op[0], op[1], op[2], op[3]};
    *(float4*)(Cbuf + ((size_t)(head * CH + cc) * 128 + y_out) * 128 + x0 + n) = o4;
  }
}

// ---------------- launch ----------------
extern "C" void kernel_launch(void* const* d_in, const int* in_sizes, int n_in,
                              void* d_out, int out_size, void* d_ws, size_t ws_size,
                              hipStream_t stream) {
  const float* x = (const float*)d_in[0];
  const float* w_qkv = (const float*)d_in[1];
  const float* w_dw = (const float*)d_in[2];
  const float* w_proj = (const float*)d_in[3];
  const float* temp = (const float*)d_in[4];
  const float* a1 = (const float*)d_in[5];
  const float* a2 = (const float*)d_in[6];
  const float* a3 = (const float*)d_in[7];
  const float* a4 = (const float*)d_in[8];
  float* out = (float*)d_out;

  // ws layout (bytes):
  //   [0,         9437184)  cattn_part f32 (128*8*2304)
  //   [9437184,   9510912)  W48 f32
  //   [9510912,   9513984)  sumsq f32 (768)
  //   [9513984,  10398720)  wqkv_h bf16 bits (1152x384)
  //   [10398720, 11283456)  wqkv_l
  //   [11283456, 11578368)  wproj_h (384x384)
  //   [11578368, 11873280)  wproj_l
  //   [11873280, 87370752)  Bq f32 (1152x16384) = 75.5 MB
  //     Xtg hi/lo in Bq v-third during qkv phase; Ctg hi/lo in q-third for proj.
  // Peak 87.4 MB (<= proven 89.4 MB).
  char* ws = (char*)d_ws;
  float* cattn_part = (float*)ws;
  float* W48 = (float*)(ws + 9437184);
  float* sumsq = (float*)(ws + 9510912);
  unsigned short* wqkv_h = (unsigned short*)(ws + 9513984);
  unsigned short* wqkv_l = (unsigned short*)(ws + 10398720);
  unsigned short* wproj_h = (unsigned short*)(ws + 11283456);
  unsigned short* wproj_l = (unsigned short*)(ws + 11578368);
  float* Bq = (float*)(ws + 11873280);
  short8* Xtgh = (short8*)(ws + 11873280 + (size_t)2 * CDIM * HW * 4);
  short8* Xtgl = (short8*)(ws + 11873280 + (size_t)2 * CDIM * HW * 4 + 12582912);
  short8* Ctgh = (short8*)(ws + 11873280);
  short8* Ctgl = (short8*)(ws + 11873280 + 12582912);

  decomp_all<<<(4 * CDIM * CDIM + 255) / 256, 256, 0, stream>>>(
      w_qkv, w_proj, wqkv_h, wqkv_l, wproj_h, wproj_l);

  for (int b = 0; b < 2; b++) {
    const float* xb = x + (size_t)b * CDIM * HW;
    float* ob = out + (size_t)b * CDIM * HW;

    transpose_frag<<<3072, 256, 0, stream>>>(xb, Xtgh, Xtgl, sumsq);  // zeroes sumsq
    for (int t = 0; t < 3; t++) {
      gemm_mfma<<<dim3(HW / 128, CDIM / 64), 256, 0, stream>>>(
          wqkv_h + (size_t)t * CDIM * CDIM, wqkv_l + (size_t)t * CDIM * CDIM,
          Xtgh, Xtgl, ob);
      dwconv3<<<(CDIM * HW / 4) / 256, 256, 0, stream>>>(
          ob, w_dw + (size_t)t * CDIM * 9, Bq + (size_t)t * CDIM * HW);
    }

    cattn_partial<<<dim3(NCHUNK, NHEADS), 256, 0, stream>>>(Bq, cattn_part, sumsq);
    chan_softmax<<<NHEADS * 48, 64, 0, stream>>>(cattn_part, sumsq, temp, a1, a2, a3, a4, W48);
    spatial_kernel<<<NHEADS * 256, 256, 0, stream>>>(Bq, W48, temp, a1, a2, a3, a4, ob);

    transpose_frag<<<3072, 256, 0, stream>>>(ob, Ctgh, Ctgl, sumsq);
    gemm_mfma<<<dim3(HW / 128, CDIM / 64), 256, 0, stream>>>(wproj_h, wproj_l,
                                                             Ctgh, Ctgl, ob);
  }

  (void)in_sizes; (void)n_in; (void)out_size; (void)ws_size;
}